// Round 5
// baseline (493.539 us; speedup 1.0000x reference)
//
#include <hip/hip_runtime.h>
#include <hip/hip_bf16.h>

typedef __attribute__((ext_vector_type(8))) __bf16 bf16x8;
typedef __attribute__((ext_vector_type(4))) float f32x4;
typedef __attribute__((ext_vector_type(4))) short sh4;
typedef __attribute__((ext_vector_type(8))) short sh8;

#define MFMA(a, b, c) __builtin_amdgcn_mfma_f32_16x16x32_bf16(a, b, c, 0, 0, 0)

#if __has_builtin(__builtin_amdgcn_exp2f)
#define EXP2(x) __builtin_amdgcn_exp2f(x)
#else
#define EXP2(x) exp2f(x)
#endif

// K=32 B-frag / V-frag pairing: slot s = lg*8 + c*4 + r <-> kv-row c*16 + lg*4 + r.
// (kv is a contraction index; P and V use the same permutation, so this is exact.)
union P8 { struct { sh4 lo, hi; } p; sh8 v; };

// Packed f32->bf16 (v_cvt_pk_bf16_f32): 4 floats -> sh4 in 2 insts.
__device__ __forceinline__ sh4 pk4(float a, float b, float c, float d) {
    __hip_bfloat162 lo = __float22bfloat162_rn(float2{a, b});
    __hip_bfloat162 hi = __float22bfloat162_rn(float2{c, d});
    union { struct { __hip_bfloat162 lo, hi; } p; sh4 s; } u;
    u.p.lo = lo; u.p.hi = hi;
    return u.s;
}

__device__ __forceinline__ float ldany(const void* p, size_t i, bool f32) {
    return f32 ? ((const float*)p)[i] : (float)(((const __bf16*)p)[i]);
}

// ---------------------------------------------------------------------------
// Merged detect + small-conversions (one launch). offsets: bq 1024, bk 2048,
// bv 3072, bo 4096, b1 5120(4096), b2 9216, ln1a 10240..ln2b 10243.
__global__ void prep_k(const void* wq, float* flag,
                       const void* bq, const void* bk, const void* bv, const void* bo,
                       const void* b1, const void* b2,
                       const void* l1a, const void* l1b, const void* l2a, const void* l2b,
                       __bf16* dst) {
    __shared__ float red[256];
    __shared__ float fls;
    int tid = threadIdx.x;
    const __bf16* p = (const __bf16*)wq;
    float mx = 0.f;
    for (int i = tid; i < 1024; i += 256) {
        float v = (float)p[i];
        if (v != v) mx = 2.f;
        v = fabsf(v);
        if (v > mx) mx = v;
    }
    red[tid] = mx;
    __syncthreads();
    for (int s = 128; s > 0; s >>= 1) {
        if (tid < s) red[tid] = fmaxf(red[tid], red[tid + s]);
        __syncthreads();
    }
    if (tid == 0) { fls = (red[0] > 1.0f) ? 1.f : 0.f; *flag = fls; }
    __syncthreads();
    bool f32 = fls > 0.5f;
    const void* srcs[10] = {bq, bk, bv, bo, b1, b2, l1a, l1b, l2a, l2b};
    const int offs[10] = {1024, 2048, 3072, 4096, 5120, 9216, 10240, 10241, 10242, 10243};
    const int ns[10]   = {1024, 1024, 1024, 1024, 4096, 1024, 1, 1, 1, 1};
    for (int t = 0; t < 10; ++t)
        for (int j = tid; j < ns[t]; j += blockDim.x)
            dst[offs[t] + j] = (__bf16)ldany(srcs[t], j, f32);
}

// ---------------------------------------------------------------------------
__device__ __forceinline__ void tr_body(const void* in, __bf16* out, int R, int C, bool f32,
                                        int bx, int by, int x, int y) {
    __shared__ __bf16 t[32][33];
    for (int i = 0; i < 32; i += 8)
        t[y + i][x] = (__bf16)ldany(in, (size_t)(by + y + i) * C + bx + x, f32);
    __syncthreads();
    for (int i = 0; i < 32; i += 8)
        out[(size_t)(bx + y + i) * R + by + x] = t[x][y + i];
}

__global__ void transpose_cvt(const void* in, __bf16* out, int R, int C, const float* flag) {
    tr_body(in, out, R, C, *flag > 0.5f, blockIdx.x * 32, blockIdx.y * 32,
            threadIdx.x, threadIdx.y);
}

__global__ void transpose4_cvt(const void* i0, const void* i1, const void* i2, const void* i3,
                               __bf16* o0, __bf16* o1, __bf16* o2, __bf16* o3,
                               const float* flag) {
    const void* in = blockIdx.z == 0 ? i0 : blockIdx.z == 1 ? i1 : blockIdx.z == 2 ? i2 : i3;
    __bf16* out = blockIdx.z == 0 ? o0 : blockIdx.z == 1 ? o1 : blockIdx.z == 2 ? o2 : o3;
    tr_body(in, out, 1024, 1024, *flag > 0.5f, blockIdx.x * 32, blockIdx.y * 32,
            threadIdx.x, threadIdx.y);
}

// ---------------------------------------------------------------------------
__global__ __launch_bounds__(256) void layernorm_k(const void* x, int xmode, const float* flag,
                                                   __bf16* out,
                                                   const __bf16* alpha, const __bf16* beta) {
    int row = blockIdx.x * 4 + (threadIdx.x >> 6);
    int lane = threadIdx.x & 63;
    bool f32 = xmode && (*flag > 0.5f);
    float v[16];
    if (f32) {
        const float4* xr = (const float4*)((const float*)x + (size_t)row * 1024 + lane * 16);
#pragma unroll
        for (int q = 0; q < 4; ++q) {
            float4 r = xr[q];
            v[q * 4 + 0] = r.x; v[q * 4 + 1] = r.y; v[q * 4 + 2] = r.z; v[q * 4 + 3] = r.w;
        }
    } else {
        const __bf16* xr = (const __bf16*)x + (size_t)row * 1024 + lane * 16;
        bf16x8 h0 = *(const bf16x8*)xr;
        bf16x8 h1 = *(const bf16x8*)(xr + 8);
#pragma unroll
        for (int i = 0; i < 8; ++i) { v[i] = (float)h0[i]; v[8 + i] = (float)h1[i]; }
    }
    float s = 0.f, ss = 0.f;
#pragma unroll
    for (int i = 0; i < 16; ++i) { s += v[i]; ss += v[i] * v[i]; }
#pragma unroll
    for (int o = 1; o < 64; o <<= 1) { s += __shfl_xor(s, o); ss += __shfl_xor(ss, o); }
    float mu = s * (1.f / 1024.f);
    float var = (ss - 1024.f * mu * mu) * (1.f / 1023.f);
    float inv = 1.f / (sqrtf(var) + 1e-6f);
    float al = (float)alpha[0], be = (float)beta[0];
    bf16x8 o0, o1;
#pragma unroll
    for (int i = 0; i < 8; ++i) {
        o0[i] = (__bf16)((v[i] - mu) * inv * al + be);
        o1[i] = (__bf16)((v[8 + i] - mu) * inv * al + be);
    }
    __bf16* orow = out + (size_t)row * 1024;
    *(bf16x8*)(orow + lane * 16) = o0;
    *(bf16x8*)(orow + lane * 16 + 8) = o1;
}

// Swizzled-tile store helpers: 64x64 tiles, chunk (8 halves) XOR'd by row&7.
__device__ __forceinline__ void swz_store(__bf16* buf, int hh, int ktt, int rr2, int cc2,
                                          float v) {
    size_t off = (((size_t)hh * 64 + ktt) << 12) + rr2 * 64 +
                 (((cc2 >> 3) ^ (rr2 & 7)) << 3) + (cc2 & 7);
    buf[off] = (__bf16)v;
}

// ---------------------------------------------------------------------------
// GEMM 128x128 (256 thr), RING-3 staging: stage tile t+2 while computing t.
// Tile-t loads were issued TWO iterations ago (~2x compute-phase slack >= L2/
// L3 latency), wait is vmcnt(2L=8), never 0 in steady state.
// swz: 0 none; 1 = QKV-fused: col<1024 Q (compact stride 1024), 1024..2047 ->
// Kswz, >=2048 -> Vswz (=swzbuf+4M) transposed.
// ---------------------------------------------------------------------------
__global__ __launch_bounds__(256) void gemm_bt(const __bf16* __restrict__ A, int lda,
                                               const __bf16* __restrict__ Bt, int ldb,
                                               const __bf16* __restrict__ bias_n,
                                               const __bf16* __restrict__ bias_m,
                                               const void* res, int res_mode,
                                               const float* flag,
                                               void* C, int out_pf,
                                               int M, int N, int K, int relu,
                                               __bf16* swzbuf, int swz) {
    __shared__ __bf16 As[3][128 * 32];
    __shared__ __bf16 Bs[3][128 * 32];
    const int tid = threadIdx.x;
    const int m0 = blockIdx.y * 128;
    const int n0 = blockIdx.x * 128;
    const int w = tid >> 6, lane = tid & 63;
    const int wr = (w >> 1) * 64, wc = (w & 1) * 64;
    const int lm = lane & 15, lg = lane >> 4;
    const bool f32 = *flag > 0.5f;
    const bool rf32 = (res_mode == 2) && f32;
    const bool of32 = out_pf && f32;

    auto stage = [&](int buf, int k0) {
#pragma unroll
        for (int i = 0; i < 2; ++i) {
            int c = i * 256 + tid;
            int row = c >> 2, kk = (c & 3) * 8;
            __builtin_amdgcn_global_load_lds(
                (const __attribute__((address_space(1))) void*)(A + (size_t)(m0 + row) * lda + k0 + kk),
                (__attribute__((address_space(3))) void*)(As[buf] + c * 8), 16, 0, 0);
            __builtin_amdgcn_global_load_lds(
                (const __attribute__((address_space(1))) void*)(Bt + (size_t)(n0 + row) * ldb + k0 + kk),
                (__attribute__((address_space(3))) void*)(Bs[buf] + c * 8), 16, 0, 0);
        }
    };

    f32x4 acc[4][4] = {};
    stage(0, 0);
    if (K > 32) stage(1, 32);
    int t = 0;
    for (int k0 = 0; k0 < K; k0 += 32, ++t) {
        int cur = t % 3;
        if (k0 + 64 < K) {
            stage((t + 2) % 3, k0 + 64);
            asm volatile("s_waitcnt vmcnt(8)" ::: "memory");   // t landed; t+1,t+2 in flight
        } else if (k0 + 32 < K) {
            asm volatile("s_waitcnt vmcnt(4)" ::: "memory");   // t landed; t+1 in flight
        } else {
            asm volatile("s_waitcnt vmcnt(0)" ::: "memory");
        }
        __builtin_amdgcn_s_barrier();
        bf16x8 a[4], b[4];
#pragma unroll
        for (int q = 0; q < 4; ++q)
            a[q] = *(const bf16x8*)(As[cur] + (wr + q * 16 + lm) * 32 + lg * 8);
#pragma unroll
        for (int q = 0; q < 4; ++q)
            b[q] = *(const bf16x8*)(Bs[cur] + (wc + q * 16 + lm) * 32 + lg * 8);
#pragma unroll
        for (int mt = 0; mt < 4; ++mt)
#pragma unroll
            for (int nt = 0; nt < 4; ++nt)
                acc[mt][nt] = MFMA(a[mt], b[nt], acc[mt][nt]);
        asm volatile("s_waitcnt lgkmcnt(0)" ::: "memory");     // my ds_reads complete
        __builtin_amdgcn_sched_barrier(0);
        __builtin_amdgcn_s_barrier();                          // buf[cur] free next iter+1
    }
#pragma unroll
    for (int mt = 0; mt < 4; ++mt) {
#pragma unroll
        for (int nt = 0; nt < 4; ++nt) {
            int col = n0 + wc + nt * 16 + lm;
            float bn = bias_n ? (float)bias_n[col] : 0.f;
#pragma unroll
            for (int r = 0; r < 4; ++r) {
                int row = m0 + wr + mt * 16 + lg * 4 + r;
                float vv = acc[mt][nt][r] + bn;
                if (bias_m) vv += (float)bias_m[row];
                if (relu) vv = fmaxf(vv, 0.f);
                if (swz == 1) {
                    if (col >= 2048) {          // V: transposed into Vswz
                        int d = col - 2048;
                        swz_store(swzbuf + (1u << 22), d >> 6, row >> 6, d & 63, row & 63, vv);
                    } else if (col >= 1024) {   // K: swizzled
                        swz_store(swzbuf, (col - 1024) >> 6, row >> 6, row & 63, (col - 1024) & 63, vv);
                    } else {                    // Q: compact stride-1024
                        ((__bf16*)C)[(size_t)row * 1024 + col] = (__bf16)vv;
                    }
                } else if (swz == 2) {
                    swz_store(swzbuf, row >> 6, col >> 6, row & 63, col & 63, vv);
                } else {
                    size_t idx = (size_t)row * N + col;
                    if (res_mode) vv += rf32 ? ((const float*)res)[idx]
                                             : (float)(((const __bf16*)res)[idx]);
                    if (of32) ((float*)C)[idx] = vv;
                    else ((__bf16*)C)[idx] = (__bf16)vv;
                }
            }
        }
    }
}

// ---------------------------------------------------------------------------
// GEMM 128x64 (256 thr), BK=64, RING-3 staging (72 KiB LDS), vmcnt(2L=12).
// Chunk-XOR swizzle via pre-swizzled GLOBAL source (linear LDS dest) and on
// the ds_read side.
// ---------------------------------------------------------------------------
__global__ __launch_bounds__(256) void gemm_n64(const __bf16* __restrict__ A, int lda,
                                                const __bf16* __restrict__ Bt, int ldb,
                                                const __bf16* __restrict__ bias_n,
                                                const __bf16* __restrict__ bias_m,
                                                const void* res, int res_mode,
                                                const float* flag,
                                                void* C, int out_pf,
                                                int M, int N, int K, int relu,
                                                __bf16* swzbuf, int swz) {
    __shared__ __bf16 As[3][128 * 64];
    __shared__ __bf16 Bs[3][64 * 64];
    const int tid = threadIdx.x;
    const int m0 = blockIdx.y * 128;
    const int n0 = blockIdx.x * 64;
    const int w = tid >> 6, lane = tid & 63;
    const int wr = (w >> 1) * 64, wc = (w & 1) * 32;
    const int lm = lane & 15, lg = lane >> 4;
    const int sw = lm & 7;
    const bool f32 = *flag > 0.5f;
    const bool rf32 = (res_mode == 2) && f32;
    const bool of32 = out_pf && f32;

    auto stage = [&](int buf, int k0) {
#pragma unroll
        for (int i = 0; i < 4; ++i) {
            int c = i * 256 + tid;
            int row = c >> 3, ch = c & 7;
            __builtin_amdgcn_global_load_lds(
                (const __attribute__((address_space(1))) void*)(A + (size_t)(m0 + row) * lda + k0 + ((ch ^ (row & 7)) << 3)),
                (__attribute__((address_space(3))) void*)(As[buf] + c * 8), 16, 0, 0);
        }
#pragma unroll
        for (int i = 0; i < 2; ++i) {
            int c = i * 256 + tid;
            int row = c >> 3, ch = c & 7;
            __builtin_amdgcn_global_load_lds(
                (const __attribute__((address_space(1))) void*)(Bt + (size_t)(n0 + row) * ldb + k0 + ((ch ^ (row & 7)) << 3)),
                (__attribute__((address_space(3))) void*)(Bs[buf] + c * 8), 16, 0, 0);
        }
    };

    f32x4 acc[4][2] = {};
    stage(0, 0);
    if (K > 64) stage(1, 64);
    int t = 0;
    for (int k0 = 0; k0 < K; k0 += 64, ++t) {
        int cur = t % 3;
        if (k0 + 128 < K) {
            stage((t + 2) % 3, k0 + 128);
            asm volatile("s_waitcnt vmcnt(12)" ::: "memory");  // t landed; t+1,t+2 in flight
        } else if (k0 + 64 < K) {
            asm volatile("s_waitcnt vmcnt(6)" ::: "memory");
        } else {
            asm volatile("s_waitcnt vmcnt(0)" ::: "memory");
        }
        __builtin_amdgcn_s_barrier();
        bf16x8 a[4][2], b[2][2];
#pragma unroll
        for (int q = 0; q < 4; ++q)
#pragma unroll
            for (int h = 0; h < 2; ++h)
                a[q][h] = *(const bf16x8*)(As[cur] + (wr + q * 16 + lm) * 64 + ((((h << 2) | lg) ^ sw) << 3));
#pragma unroll
        for (int q = 0; q < 2; ++q)
#pragma unroll
            for (int h = 0; h < 2; ++h)
                b[q][h] = *(const bf16x8*)(Bs[cur] + (wc + q * 16 + lm) * 64 + ((((h << 2) | lg) ^ sw) << 3));
#pragma unroll
        for (int mt = 0; mt < 4; ++mt)
#pragma unroll
            for (int nt = 0; nt < 2; ++nt) {
                acc[mt][nt] = MFMA(a[mt][0], b[nt][0], acc[mt][nt]);
                acc[mt][nt] = MFMA(a[mt][1], b[nt][1], acc[mt][nt]);
            }
        asm volatile("s_waitcnt lgkmcnt(0)" ::: "memory");
        __builtin_amdgcn_sched_barrier(0);
        __builtin_amdgcn_s_barrier();
    }
#pragma unroll
    for (int mt = 0; mt < 4; ++mt) {
#pragma unroll
        for (int nt = 0; nt < 2; ++nt) {
            int col = n0 + wc + nt * 16 + lm;
            float bn = bias_n ? (float)bias_n[col] : 0.f;
#pragma unroll
            for (int r = 0; r < 4; ++r) {
                int row = m0 + wr + mt * 16 + lg * 4 + r;
                float vv = acc[mt][nt][r] + bn;
                if (bias_m) vv += (float)bias_m[row];
                if (relu) vv = fmaxf(vv, 0.f);
                if (swz == 2) {
                    swz_store(swzbuf, row >> 6, col >> 6, row & 63, col & 63, vv);
                } else {
                    size_t idx = (size_t)row * N + col;
                    if (res_mode) vv += rf32 ? ((const float*)res)[idx]
                                             : (float)(((const __bf16*)res)[idx]);
                    if (of32) ((float*)C)[idx] = vv;
                    else ((__bf16*)C)[idx] = (__bf16)vv;
                }
            }
        }
    }
}

// ---------------------------------------------------------------------------
// Attention v7: K=32 PV via kv-permutation. P B-frags are register concats of
// the two pk4 outputs of adjacent 16-chunks; V A-frags read the SAME four sh4s
// per lane as the K=16 version, re-paired. PV+rowsum: 20 MFMAs/tile (was 48).
// ---------------------------------------------------------------------------
__global__ __launch_bounds__(256) void attn_ks2(const __bf16* __restrict__ Q, int ldq,
                                                const __bf16* __restrict__ Kswz,
                                                const __bf16* __restrict__ Vswz,
                                                __bf16* __restrict__ Opart,
                                                float* __restrict__ lpart) {
    constexpr int S = 4096;
    __shared__ __bf16 lds[2 * 8192];   // [buf][K tile 4096 | V tile 4096]
    const int h = blockIdx.y, z = blockIdx.z;
    const int q0 = blockIdx.x * 128;
    const int tid = threadIdx.x, w = tid >> 6, lane = tid & 63;
    const int lm = lane & 15, lg = lane >> 4;

    const __bf16* gK = Kswz + (((size_t)h * 64 + z * 32) << 12);
    const __bf16* gV = Vswz + (((size_t)h * 64 + z * 32) << 12);

    // Q B-frags (n=lm is q), pre-scaled by 0.125*log2e.
    bf16x8 qf[2][2];
#pragma unroll
    for (int qc = 0; qc < 2; ++qc) {
        const __bf16* qp = Q + (size_t)(q0 + w * 32 + qc * 16 + lm) * ldq + h * 64;
        qf[qc][0] = *(const bf16x8*)(qp + lg * 8);
        qf[qc][1] = *(const bf16x8*)(qp + 32 + lg * 8);
#pragma unroll
        for (int hh = 0; hh < 2; ++hh) {
            bf16x8 t = qf[qc][hh];
#pragma unroll
            for (int i = 0; i < 8; ++i) t[i] = (__bf16)((float)t[i] * 0.1803368801f);
            qf[qc][hh] = t;
        }
    }
    bf16x8 ones8;
#pragma unroll
    for (int i = 0; i < 8; ++i) ones8[i] = (__bf16)1.f;

    f32x4 o_[4][2] = {};
    f32x4 l_[2] = {};

    auto issue = [&](int t) {
        __bf16* dK = lds + (t & 1) * 8192;
        __bf16* dV = dK + 4096;
        const __bf16* sK = gK + ((size_t)t << 12);
        const __bf16* sV = gV + ((size_t)t << 12);
#pragma unroll
        for (int i = 0; i < 2; ++i) {
            int c = i * 256 + tid;
            __builtin_amdgcn_global_load_lds(
                (const __attribute__((address_space(1))) void*)(sK + c * 8),
                (__attribute__((address_space(3))) void*)(dK + c * 8), 16, 0, 0);
            __builtin_amdgcn_global_load_lds(
                (const __attribute__((address_space(1))) void*)(sV + c * 8),
                (__attribute__((address_space(3))) void*)(dV + c * 8), 16, 0, 0);
        }
    };
    issue(0);
    for (int t = 0; t < 32; ++t) {
        __syncthreads();                 // drains DMA for tile t; closes prev compute
        if (t < 31) issue(t + 1);        // in flight across this tile's compute
        const __bf16* Kt = lds + (t & 1) * 8192;
        const __bf16* Vt = Kt + 4096;

        P8 pb[2][2];
#pragma unroll
        for (int mt = 0; mt < 4; ++mt) {
            int rr = mt * 16 + lm;
            const __bf16* kr = Kt + rr * 64;
            bf16x8 kf0 = *(const bf16x8*)(kr + ((lg ^ (rr & 7)) << 3));
            bf16x8 kf1 = *(const bf16x8*)(kr + (((4 + lg) ^ (rr & 7)) << 3));
#pragma unroll
            for (int qc = 0; qc < 2; ++qc) {
                f32x4 s = (f32x4){0.f, 0.f, 0.f, 0.f};
                s = MFMA(kf0, qf[qc][0], s);
                s = MFMA(kf1, qf[qc][1], s);
                sh4 e = pk4(EXP2(s[0]), EXP2(s[1]), EXP2(s[2]), EXP2(s[3]));
                if (mt & 1) pb[mt >> 1][qc].p.hi = e;
                else        pb[mt >> 1][qc].p.lo = e;
            }
        }
#pragma unroll
        for (int mtd = 0; mtd < 4; ++mtd) {
            int rr = mtd * 16 + lm;
            const __bf16* vr = Vt + rr * 64;
#pragma unroll
            for (int cp = 0; cp < 2; ++cp) {
                int cbase = cp * 4 + (lg >> 1);
                P8 va;
                va.p.lo = *(const sh4*)(vr + ((cbase ^ (rr & 7)) << 3) + (lg & 1) * 4);
                va.p.hi = *(const sh4*)(vr + (((cbase + 2) ^ (rr & 7)) << 3) + (lg & 1) * 4);
                bf16x8 vab = __builtin_bit_cast(bf16x8, va.v);
                o_[mtd][0] = MFMA(vab, __builtin_bit_cast(bf16x8, pb[cp][0].v), o_[mtd][0]);
                o_[mtd][1] = MFMA(vab, __builtin_bit_cast(bf16x8, pb[cp][1].v), o_[mtd][1]);
            }
        }
#pragma unroll
        for (int cp = 0; cp < 2; ++cp) {
            l_[0] = MFMA(ones8, __builtin_bit_cast(bf16x8, pb[cp][0].v), l_[0]);
            l_[1] = MFMA(ones8, __builtin_bit_cast(bf16x8, pb[cp][1].v), l_[1]);
        }
    }

    // Unnormalized O^T -> lds[128][72] (packed 8B stores) -> coalesced store.
    __syncthreads();
#pragma unroll
    for (int qc = 0; qc < 2; ++qc) {
#pragma unroll
        for (int mtd = 0; mtd < 4; ++mtd) {
            sh4 ov = pk4(o_[mtd][qc][0], o_[mtd][qc][1], o_[mtd][qc][2], o_[mtd][qc][3]);
            *(sh4*)(lds + (w * 32 + qc * 16 + lm) * 72 + mtd * 16 + lg * 4) = ov;
        }
        if (lg == 0)
            lpart[(size_t)(h * 2 + z) * S + q0 + w * 32 + qc * 16 + lm] = l_[qc][0];
    }
    __syncthreads();
    __bf16* Ob = Opart + (((size_t)(h * 2 + z) * S + q0) << 6);
    int row = tid >> 1, co = (tid & 1) * 32;
#pragma unroll
    for (int b = 0; b < 4; ++b)
        *(uint4*)(Ob + row * 64 + co + b * 8) = *(const uint4*)(lds + row * 72 + co + b * 8);
}

__global__ __launch_bounds__(256) void attn_comb(const __bf16* __restrict__ Opart,
                                                 const float* __restrict__ lpart,
                                                 __bf16* __restrict__ ctx) {
    constexpr int S = 4096;
#pragma unroll
    for (int it = 0; it < 4; ++it) {
        int task = blockIdx.x * 1024 + it * 256 + threadIdx.x;  // (q, c8)
        int q = task >> 7, c8 = task & 127, h = c8 >> 3, d8 = (c8 & 7) * 8;
        const __bf16* p0 = Opart + (((size_t)(h * 2 + 0) * S + q) << 6) + d8;
        const __bf16* p1 = Opart + (((size_t)(h * 2 + 1) * S + q) << 6) + d8;
        float inv = 1.f / (lpart[(size_t)(h * 2 + 0) * S + q] + lpart[(size_t)(h * 2 + 1) * S + q]);
        bf16x8 a = *(const bf16x8*)p0, b = *(const bf16x8*)p1, o;
#pragma unroll
        for (int i = 0; i < 8; ++i) o[i] = (__bf16)(((float)a[i] + (float)b[i]) * inv);
        *(bf16x8*)(ctx + (size_t)q * 1024 + c8 * 8) = o;
    }
}

// ---------------------------------------------------------------------------
// r6 attention (padded-LDS, no split) — fallback path only. Same K=32 PV.
// ---------------------------------------------------------------------------
__global__ __launch_bounds__(256) void attn_v3(const __bf16* __restrict__ Q, int ldq,
                                               const __bf16* __restrict__ Kg, int ldk,
                                               const __bf16* __restrict__ VT,
                                               __bf16* __restrict__ ctx) {
    constexpr int S = 4096, D = 1024, LDT = 72;
    __shared__ __bf16 lds[128 * LDT];
    __bf16* Kt = lds;
    __bf16* Vt = lds + 64 * LDT;
    const int h = blockIdx.y;
    const int q0 = blockIdx.x * 128;
    const int tid = threadIdx.x, w = tid >> 6, lane = tid & 63;
    const int lm = lane & 15, lg = lane >> 4;
    bf16x8 qf[2][2];
#pragma unroll
    for (int qc = 0; qc < 2; ++qc) {
        const __bf16* qp = Q + (size_t)(q0 + w * 32 + qc * 16 + lm) * ldq + h * 64;
        qf[qc][0] = *(const bf16x8*)(qp + lg * 8);
        qf[qc][1] = *(const bf16x8*)(qp + 32 + lg * 8);
#pragma unroll
        for (int hh = 0; hh < 2; ++hh) {
            bf16x8 t = qf[qc][hh];
#pragma unroll
            for (int i = 0; i < 8; ++i) t[i] = (__bf16)((float)t[i] * 0.1803368801f);
            qf[qc][hh] = t;
        }
    }
    bf16x8 ones8;
#pragma unroll
    for (int i = 0; i < 8; ++i) ones8[i] = (__bf16)1.f;
    f32x4 o_[4][2] = {};
    f32x4 l_[2] = {};
    for (int kt = 0; kt < S / 64; ++kt) {
        __syncthreads();
#pragma unroll
        for (int i = 0; i < 2; ++i) {
            int c = i * 256 + tid;
            int rr = c >> 3, cc = (c & 7) * 8;
            *(uint4*)(Kt + rr * LDT + cc) =
                *(const uint4*)(Kg + (size_t)(kt * 64 + rr) * ldk + h * 64 + cc);
            *(uint4*)(Vt + rr * LDT + cc) =
                *(const uint4*)(VT + (size_t)(h * 64 + rr) * S + kt * 64 + cc);
        }
        __syncthreads();
        P8 pb[2][2];
#pragma unroll
        for (int mt = 0; mt < 4; ++mt) {
            bf16x8 kf0 = *(const bf16x8*)(Kt + (mt * 16 + lm) * LDT + lg * 8);
            bf16x8 kf1 = *(const bf16x8*)(Kt + (mt * 16 + lm) * LDT + 32 + lg * 8);
#pragma unroll
            for (int qc = 0; qc < 2; ++qc) {
                f32x4 s = (f32x4){0.f, 0.f, 0.f, 0.f};
                s = MFMA(kf0, qf[qc][0], s);
                s = MFMA(kf1, qf[qc][1], s);
                sh4 e = pk4(EXP2(s[0]), EXP2(s[1]), EXP2(s[2]), EXP2(s[3]));
                if (mt & 1) pb[mt >> 1][qc].p.hi = e;
                else        pb[mt >> 1][qc].p.lo = e;
            }
        }
#pragma unroll
        for (int mtd = 0; mtd < 4; ++mtd) {
            const __bf16* vrow = Vt + (mtd * 16 + lm) * LDT;
#pragma unroll
            for (int cp = 0; cp < 2; ++cp) {
                P8 va;
                va.p.lo = *(const sh4*)(vrow + cp * 32 + lg * 4);
                va.p.hi = *(const sh4*)(vrow + cp * 32 + 16 + lg * 4);
                bf16x8 vab = __builtin_bit_cast(bf16x8, va.v);
                o_[mtd][0] = MFMA(vab, __builtin_bit_cast(bf16x8, pb[cp][0].v), o_[mtd][0]);
                o_[mtd][1] = MFMA(vab, __builtin_bit_cast(bf16x8, pb[cp][1].v), o_[mtd][1]);
            }
        }
#pragma unroll
        for (int cp = 0; cp < 2; ++cp) {
            l_[0] = MFMA(ones8, __builtin_bit_cast(bf16x8, pb[cp][0].v), l_[0]);
            l_[1] = MFMA(ones8, __builtin_bit_cast(bf16x8, pb[cp][1].v), l_[1]);
        }
    }
    __syncthreads();
    float inv[2] = {1.f / l_[0][0], 1.f / l_[1][0]};
#pragma unroll
    for (int qc = 0; qc < 2; ++qc)
#pragma unroll
        for (int mtd = 0; mtd < 4; ++mtd)
#pragma unroll
            for (int r = 0; r < 4; ++r)
                lds[(w * 32 + qc * 16 + lm) * LDT + mtd * 16 + lg * 4 + r] =
                    (__bf16)(o_[mtd][qc][r] * inv[qc]);
    __syncthreads();
    int row = tid >> 1, cb = (tid & 1) * 32;
#pragma unroll
    for (int b = 0; b < 4; ++b)
        *(uint4*)(ctx + (size_t)(q0 + row) * D + h * 64 + cb + b * 8) =
            *(const uint4*)(lds + row * LDT + cb + b * 8);
}

// ---------------------------------------------------------------------------
extern "C" void kernel_launch(void* const* d_in, const int* in_sizes, int n_in,
                              void* d_out, int out_size, void* d_ws, size_t ws_size,
                              hipStream_t stream) {
    const void* x    = d_in[0];
    const void* Wq   = d_in[1];
    const void* bq   = d_in[2];
    const void* Wk   = d_in[3];
    const void* bk   = d_in[4];
    const void* Wv   = d_in[5];
    const void* bv   = d_in[6];
    const void* Wo   = d_in[7];
    const void* bo   = d_in[8];
    const void* ln1a = d_in[9];
    const void* ln1b = d_in[10];
    const void* W1   = d_in[11];
    const void* b1   = d_in[12];
    const void* W2   = d_in[13];
    const void* b2   = d_in[14];
    const void* ln2a = d_in[15];
    const void* ln2b = d_in[16];

    constexpr size_t M1 = 1u << 20;
    __bf16* ws = (__bf16*)d_ws;
    float* flagF = (float*)ws;
    __bf16* bmir = ws;
    dim3 tb(32, 8);
    const bool big = ws_size >= (size_t)(32.25 * 2 * M1) + 4096;

    prep_k<<<1, 256, 0, stream>>>(Wq, flagF, bq, bk, bv, bo, b1, b2,
                                  ln1a, ln1b, ln2a, ln2b, bmir);

    if (big) {
        // peak 32.25M elems = 64.5 MB
        __bf16* WqT = ws + M1 / 4;     // WqT/WkT/WvT contiguous -> fused QKV B matrix
        __bf16* WkT = WqT + M1;
        __bf16* WvT = ws + 2 * M1 + M1 / 4;
        __bf16* WoT = ws + 3 * M1 + M1 / 4;
        __bf16* W2T = ws + M1 / 4;
        float* lpart = (float*)(ws + M1 / 4);
        __bf16* hb  = ws + 4 * M1 + M1 / 4;
        __bf16* h2  = hb;
        __bf16* QKb = ws + 8 * M1 + M1 / 4;
        __bf16* x2  = QKb;
        __bf16* W1T = ws + 12 * M1 + M1 / 4;
        __bf16* Kswz = ws + 16 * M1 + M1 / 4;  // Vswz = Kswz + 4M (contiguous)
        __bf16* ctx  = Kswz;
        __bf16* Vswz = ws + 20 * M1 + M1 / 4;
        __bf16* Opart = ws + 24 * M1 + M1 / 4;
        __bf16* f1  = ws + 16 * M1 + M1 / 4;

        transpose4_cvt<<<dim3(32, 32, 4), tb, 0, stream>>>(Wq, Wk, Wv, Wo,
                                                           WqT, WkT, WvT, WoT, flagF);
        layernorm_k<<<1024, 256, 0, stream>>>(x, 1, flagF, hb, bmir + 10240, bmir + 10241);
        // Fused QKV projection: N=3072 (Q compact -> QKb, K -> Kswz, V -> Vswz).
        gemm_bt<<<dim3(24, 32), 256, 0, stream>>>(hb, 1024, WqT, 1024, bmir + 1024, nullptr,
                                                  nullptr, 0, flagF, QKb, 0, 4096, 3072, 1024, 0,
                                                  Kswz, 1);
        attn_ks2<<<dim3(32, 16, 2), 256, 0, stream>>>(QKb, 1024, Kswz, Vswz, Opart, lpart);
        attn_comb<<<512, 256, 0, stream>>>(Opart, lpart, ctx);
        transpose_cvt<<<dim3(128, 32), tb, 0, stream>>>(W1, W1T, 1024, 4096, flagF);
        gemm_n64<<<dim3(16, 32), 256, 0, stream>>>(ctx, 1024, WoT, 1024, bmir + 4096, nullptr,
                                                   x, 2, flagF, x2, 0, 4096, 1024, 1024, 0,
                                                   nullptr, 0);
        transpose_cvt<<<dim3(32, 128), tb, 0, stream>>>(W2, W2T, 4096, 1024, flagF);
        layernorm_k<<<1024, 256, 0, stream>>>(x2, 0, flagF, h2, bmir + 10242, bmir + 10243);
        gemm_bt<<<dim3(32, 32), 256, 0, stream>>>(h2, 1024, W1T, 1024, bmir + 5120, nullptr,
                                                  nullptr, 0, flagF, f1, 0, 4096, 4096, 1024, 1,
                                                  nullptr, 0);
        gemm_n64<<<dim3(16, 32), 256, 0, stream>>>(f1, 4096, W2T, 4096, bmir + 9216, nullptr,
                                                   x2, 1, flagF, d_out, 1, 4096, 1024, 4096, 0,
                                                   nullptr, 0);
    } else {
        // chunked fallback (r6), peak 46.5 MB
        constexpr size_t Qn = 1u << 18;
        __bf16* WqT = ws + Qn;
        __bf16* WoT = WqT;
        __bf16* WkT = ws + 5 * Qn;
        __bf16* WvT = ws + 9 * Qn;
        __bf16* hb  = ws + 13 * Qn;
        __bf16* f1q = hb;
        __bf16* ctx = ws + 29 * Qn;
        __bf16* W2T = ctx;
        __bf16* QKb = ws + 45 * Qn;
        __bf16* x2  = QKb;
        __bf16* Kb  = ws + 61 * Qn;
        __bf16* h2  = Kb;
        __bf16* VTb = ws + 77 * Qn;
        __bf16* W1T = VTb;
        transpose_cvt<<<dim3(32, 32), tb, 0, stream>>>(Wq, WqT, 1024, 1024, flagF);
        transpose_cvt<<<dim3(32, 32), tb, 0, stream>>>(Wk, WkT, 1024, 1024, flagF);
        transpose_cvt<<<dim3(32, 32), tb, 0, stream>>>(Wv, WvT, 1024, 1024, flagF);
        layernorm_k<<<1024, 256, 0, stream>>>(x, 1, flagF, hb, bmir + 10240, bmir + 10241);
        gemm_bt<<<dim3(8, 32), 256, 0, stream>>>(hb, 1024, WqT, 1024, bmir + 1024, nullptr,
                                                 nullptr, 0, flagF, QKb, 0, 4096, 1024, 1024, 0,
                                                 nullptr, 0);
        gemm_bt<<<dim3(8, 32), 256, 0, stream>>>(hb, 1024, WkT, 1024, bmir + 2048, nullptr,
                                                 nullptr, 0, flagF, Kb, 0, 4096, 1024, 1024, 0,
                                                 nullptr, 0);
        gemm_n64<<<dim3(64, 8), 256, 0, stream>>>(WvT, 1024, hb, 1024, nullptr, bmir + 3072,
                                                  nullptr, 0, flagF, VTb, 0, 1024, 4096, 1024, 0,
                                                  nullptr, 0);
        attn_v3<<<dim3(32, 16), 256, 0, stream>>>(QKb, 1024, Kb, 1024, VTb, ctx);
        transpose_cvt<<<dim3(32, 32), tb, 0, stream>>>(Wo, WoT, 1024, 1024, flagF);
        gemm_n64<<<dim3(16, 32), 256, 0, stream>>>(ctx, 1024, WoT, 1024, bmir + 4096, nullptr,
                                                   x, 2, flagF, x2, 0, 4096, 1024, 1024, 0,
                                                   nullptr, 0);
        layernorm_k<<<1024, 256, 0, stream>>>(x2, 0, flagF, h2, bmir + 10242, bmir + 10243);
        transpose_cvt<<<dim3(128, 32), tb, 0, stream>>>(W1, W1T, 1024, 4096, flagF);
        transpose_cvt<<<dim3(32, 128), tb, 0, stream>>>(W2, W2T, 4096, 1024, flagF);
        for (int ck = 0; ck < 2; ++ck) {
            gemm_bt<<<dim3(16, 32), 256, 0, stream>>>(h2, 1024, W1T + (size_t)ck * 2048 * 1024,
                                                      1024, bmir + 5120 + ck * 2048, nullptr,
                                                      nullptr, 0, flagF, f1q, 0, 4096, 2048, 1024, 1,
                                                      nullptr, 0);
            gemm_n64<<<dim3(16, 32), 256, 0, stream>>>(f1q, 2048, W2T + ck * 2048, 4096,
                                                       ck == 0 ? bmir + 9216 : nullptr, nullptr,
                                                       x2, 1, flagF, ck == 1 ? d_out : (void*)x2,
                                                       ck == 1 ? 1 : 0, 4096, 1024, 2048, 0,
                                                       nullptr, 0);
        }
    }
}

// Round 7
// 475.239 us; speedup vs baseline: 1.0385x; 1.0385x over previous
//
#include <hip/hip_runtime.h>
#include <hip/hip_bf16.h>

typedef __attribute__((ext_vector_type(8))) __bf16 bf16x8;
typedef __attribute__((ext_vector_type(4))) float f32x4;
typedef __attribute__((ext_vector_type(4))) short sh4;
typedef __attribute__((ext_vector_type(8))) short sh8;

#define MFMA(a, b, c) __builtin_amdgcn_mfma_f32_16x16x32_bf16(a, b, c, 0, 0, 0)

#if __has_builtin(__builtin_amdgcn_exp2f)
#define EXP2(x) __builtin_amdgcn_exp2f(x)
#else
#define EXP2(x) exp2f(x)
#endif

// K=32 B-frag / V-frag pairing: slot s = lg*8 + c*4 + r <-> kv-row c*16 + lg*4 + r.
// (kv is a contraction index; P and V use the same permutation, so this is exact.)
union P8 { struct { sh4 lo, hi; } p; sh8 v; };

// Packed f32->bf16 (v_cvt_pk_bf16_f32): 4 floats -> sh4 in 2 insts.
__device__ __forceinline__ sh4 pk4(float a, float b, float c, float d) {
    __hip_bfloat162 lo = __float22bfloat162_rn(float2{a, b});
    __hip_bfloat162 hi = __float22bfloat162_rn(float2{c, d});
    union { struct { __hip_bfloat162 lo, hi; } p; sh4 s; } u;
    u.p.lo = lo; u.p.hi = hi;
    return u.s;
}

__device__ __forceinline__ float ldany(const void* p, size_t i, bool f32) {
    return f32 ? ((const float*)p)[i] : (float)(((const __bf16*)p)[i]);
}

// T1: XCD-aware bijective remap (chunked). XCD k gets a contiguous run of
// tiles -> blocks co-resident on one XCD share the same A row-panel in L2.
// Bijective when nwg%8==0 (all grids here); identity otherwise.
__device__ __forceinline__ void xcd_remap(int& bx, int& by) {
    int nx = gridDim.x;
    int nwg = nx * gridDim.y;
    int bid = by * nx + bx;
    if ((nwg & 7) == 0) {
        int id = (bid & 7) * (nwg >> 3) + (bid >> 3);
        bx = id % nx;
        by = id / nx;
    }
}

// ---------------------------------------------------------------------------
// Merged detect + small-conversions (one launch). offsets: bq 1024, bk 2048,
// bv 3072, bo 4096, b1 5120(4096), b2 9216, ln1a 10240..ln2b 10243.
__global__ void prep_k(const void* wq, float* flag,
                       const void* bq, const void* bk, const void* bv, const void* bo,
                       const void* b1, const void* b2,
                       const void* l1a, const void* l1b, const void* l2a, const void* l2b,
                       __bf16* dst) {
    __shared__ float red[256];
    __shared__ float fls;
    int tid = threadIdx.x;
    const __bf16* p = (const __bf16*)wq;
    float mx = 0.f;
    for (int i = tid; i < 1024; i += 256) {
        float v = (float)p[i];
        if (v != v) mx = 2.f;
        v = fabsf(v);
        if (v > mx) mx = v;
    }
    red[tid] = mx;
    __syncthreads();
    for (int s = 128; s > 0; s >>= 1) {
        if (tid < s) red[tid] = fmaxf(red[tid], red[tid + s]);
        __syncthreads();
    }
    if (tid == 0) { fls = (red[0] > 1.0f) ? 1.f : 0.f; *flag = fls; }
    __syncthreads();
    bool f32 = fls > 0.5f;
    const void* srcs[10] = {bq, bk, bv, bo, b1, b2, l1a, l1b, l2a, l2b};
    const int offs[10] = {1024, 2048, 3072, 4096, 5120, 9216, 10240, 10241, 10242, 10243};
    const int ns[10]   = {1024, 1024, 1024, 1024, 4096, 1024, 1, 1, 1, 1};
    for (int t = 0; t < 10; ++t)
        for (int j = tid; j < ns[t]; j += blockDim.x)
            dst[offs[t] + j] = (__bf16)ldany(srcs[t], j, f32);
}

// ---------------------------------------------------------------------------
__device__ __forceinline__ void tr_body(const void* in, __bf16* out, int R, int C, bool f32,
                                        int bx, int by, int x, int y) {
    __shared__ __bf16 t[32][33];
    for (int i = 0; i < 32; i += 8)
        t[y + i][x] = (__bf16)ldany(in, (size_t)(by + y + i) * C + bx + x, f32);
    __syncthreads();
    for (int i = 0; i < 32; i += 8)
        out[(size_t)(bx + y + i) * R + by + x] = t[x][y + i];
}

__global__ void transpose_cvt(const void* in, __bf16* out, int R, int C, const float* flag) {
    tr_body(in, out, R, C, *flag > 0.5f, blockIdx.x * 32, blockIdx.y * 32,
            threadIdx.x, threadIdx.y);
}

__global__ void transpose4_cvt(const void* i0, const void* i1, const void* i2, const void* i3,
                               __bf16* o0, __bf16* o1, __bf16* o2, __bf16* o3,
                               const float* flag) {
    const void* in = blockIdx.z == 0 ? i0 : blockIdx.z == 1 ? i1 : blockIdx.z == 2 ? i2 : i3;
    __bf16* out = blockIdx.z == 0 ? o0 : blockIdx.z == 1 ? o1 : blockIdx.z == 2 ? o2 : o3;
    tr_body(in, out, 1024, 1024, *flag > 0.5f, blockIdx.x * 32, blockIdx.y * 32,
            threadIdx.x, threadIdx.y);
}

// ---------------------------------------------------------------------------
__global__ __launch_bounds__(256) void layernorm_k(const void* x, int xmode, const float* flag,
                                                   __bf16* out,
                                                   const __bf16* alpha, const __bf16* beta) {
    int row = blockIdx.x * 4 + (threadIdx.x >> 6);
    int lane = threadIdx.x & 63;
    bool f32 = xmode && (*flag > 0.5f);
    float v[16];
    if (f32) {
        const float4* xr = (const float4*)((const float*)x + (size_t)row * 1024 + lane * 16);
#pragma unroll
        for (int q = 0; q < 4; ++q) {
            float4 r = xr[q];
            v[q * 4 + 0] = r.x; v[q * 4 + 1] = r.y; v[q * 4 + 2] = r.z; v[q * 4 + 3] = r.w;
        }
    } else {
        const __bf16* xr = (const __bf16*)x + (size_t)row * 1024 + lane * 16;
        bf16x8 h0 = *(const bf16x8*)xr;
        bf16x8 h1 = *(const bf16x8*)(xr + 8);
#pragma unroll
        for (int i = 0; i < 8; ++i) { v[i] = (float)h0[i]; v[8 + i] = (float)h1[i]; }
    }
    float s = 0.f, ss = 0.f;
#pragma unroll
    for (int i = 0; i < 16; ++i) { s += v[i]; ss += v[i] * v[i]; }
#pragma unroll
    for (int o = 1; o < 64; o <<= 1) { s += __shfl_xor(s, o); ss += __shfl_xor(ss, o); }
    float mu = s * (1.f / 1024.f);
    float var = (ss - 1024.f * mu * mu) * (1.f / 1023.f);
    float inv = 1.f / (sqrtf(var) + 1e-6f);
    float al = (float)alpha[0], be = (float)beta[0];
    bf16x8 o0, o1;
#pragma unroll
    for (int i = 0; i < 8; ++i) {
        o0[i] = (__bf16)((v[i] - mu) * inv * al + be);
        o1[i] = (__bf16)((v[8 + i] - mu) * inv * al + be);
    }
    __bf16* orow = out + (size_t)row * 1024;
    *(bf16x8*)(orow + lane * 16) = o0;
    *(bf16x8*)(orow + lane * 16 + 8) = o1;
}

// Swizzled-tile store helpers: 64x64 tiles, chunk (8 halves) XOR'd by row&7.
__device__ __forceinline__ void swz_store(__bf16* buf, int hh, int ktt, int rr2, int cc2,
                                          float v) {
    size_t off = (((size_t)hh * 64 + ktt) << 12) + rr2 * 64 +
                 (((cc2 >> 3) ^ (rr2 & 7)) << 3) + (cc2 & 7);
    buf[off] = (__bf16)v;
}

// ---------------------------------------------------------------------------
// GEMM 128x128 (256 thr), double-buffered with COUNTED vmcnt:
//   stage(k+1) -> s_waitcnt vmcnt(4) [tile-k loads done, k+1 stays in flight]
//   -> raw s_barrier -> ds_read/MFMA -> lgkmcnt(0)+sched_fence -> raw s_barrier.
// + T1 XCD-aware block remap.  swz: 0 none; 1 = cols>=1024 -> swzbuf.
// ---------------------------------------------------------------------------
__global__ __launch_bounds__(256) void gemm_bt(const __bf16* __restrict__ A, int lda,
                                               const __bf16* __restrict__ Bt, int ldb,
                                               const __bf16* __restrict__ bias_n,
                                               const __bf16* __restrict__ bias_m,
                                               const void* res, int res_mode,
                                               const float* flag,
                                               void* C, int out_pf,
                                               int M, int N, int K, int relu,
                                               __bf16* swzbuf, int swz) {
    __shared__ __bf16 As[2][128 * 32];
    __shared__ __bf16 Bs[2][128 * 32];
    const int tid = threadIdx.x;
    int bx = blockIdx.x, by = blockIdx.y;
    xcd_remap(bx, by);
    const int m0 = by * 128;
    const int n0 = bx * 128;
    const int w = tid >> 6, lane = tid & 63;
    const int wr = (w >> 1) * 64, wc = (w & 1) * 64;
    const int lm = lane & 15, lg = lane >> 4;
    const bool f32 = *flag > 0.5f;
    const bool rf32 = (res_mode == 2) && f32;
    const bool of32 = out_pf && f32;

    auto stage = [&](int buf, int k0) {
#pragma unroll
        for (int i = 0; i < 2; ++i) {
            int c = i * 256 + tid;
            int row = c >> 2, kk = (c & 3) * 8;
            __builtin_amdgcn_global_load_lds(
                (const __attribute__((address_space(1))) void*)(A + (size_t)(m0 + row) * lda + k0 + kk),
                (__attribute__((address_space(3))) void*)(As[buf] + c * 8), 16, 0, 0);
            __builtin_amdgcn_global_load_lds(
                (const __attribute__((address_space(1))) void*)(Bt + (size_t)(n0 + row) * ldb + k0 + kk),
                (__attribute__((address_space(3))) void*)(Bs[buf] + c * 8), 16, 0, 0);
        }
    };

    f32x4 acc[4][4] = {};
    stage(0, 0);
    int cur = 0;
    for (int k0 = 0; k0 < K; k0 += 32) {
        if (k0 + 32 < K) {
            stage(cur ^ 1, k0 + 32);
            asm volatile("s_waitcnt vmcnt(4)" ::: "memory");  // tile-cur landed; next in flight
        } else {
            asm volatile("s_waitcnt vmcnt(0)" ::: "memory");
        }
        __builtin_amdgcn_s_barrier();
        bf16x8 a[4], b[4];
#pragma unroll
        for (int t = 0; t < 4; ++t)
            a[t] = *(const bf16x8*)(As[cur] + (wr + t * 16 + lm) * 32 + lg * 8);
#pragma unroll
        for (int t = 0; t < 4; ++t)
            b[t] = *(const bf16x8*)(Bs[cur] + (wc + t * 16 + lm) * 32 + lg * 8);
#pragma unroll
        for (int mt = 0; mt < 4; ++mt)
#pragma unroll
            for (int nt = 0; nt < 4; ++nt)
                acc[mt][nt] = MFMA(a[mt], b[nt], acc[mt][nt]);
        asm volatile("s_waitcnt lgkmcnt(0)" ::: "memory");    // my ds_reads complete
        __builtin_amdgcn_sched_barrier(0);
        __builtin_amdgcn_s_barrier();                         // buf[cur] safe to overwrite
        cur ^= 1;
    }
#pragma unroll
    for (int mt = 0; mt < 4; ++mt) {
#pragma unroll
        for (int nt = 0; nt < 4; ++nt) {
            int col = n0 + wc + nt * 16 + lm;
            float bn = bias_n ? (float)bias_n[col] : 0.f;
#pragma unroll
            for (int r = 0; r < 4; ++r) {
                int row = m0 + wr + mt * 16 + lg * 4 + r;
                float vv = acc[mt][nt][r] + bn;
                if (bias_m) vv += (float)bias_m[row];
                if (relu) vv = fmaxf(vv, 0.f);
                if (swz == 1 && col >= 1024) {
                    swz_store(swzbuf, (col - 1024) >> 6, row >> 6, row & 63, (col - 1024) & 63, vv);
                } else if (swz == 2) {
                    swz_store(swzbuf, row >> 6, col >> 6, row & 63, col & 63, vv);
                } else {
                    size_t idx = (size_t)row * N + col;
                    if (res_mode) vv += rf32 ? ((const float*)res)[idx]
                                             : (float)(((const __bf16*)res)[idx]);
                    if (of32) ((float*)C)[idx] = vv;
                    else ((__bf16*)C)[idx] = (__bf16)vv;
                }
            }
        }
    }
}

// ---------------------------------------------------------------------------
// GEMM 128x64 (256 thr), BK=64, double-buffered, counted vmcnt(6), T1 remap.
// Chunk-XOR swizzle via pre-swizzled GLOBAL source (linear LDS dest) and on
// the ds_read side. 48 KiB LDS.
// ---------------------------------------------------------------------------
__global__ __launch_bounds__(256) void gemm_n64(const __bf16* __restrict__ A, int lda,
                                                const __bf16* __restrict__ Bt, int ldb,
                                                const __bf16* __restrict__ bias_n,
                                                const __bf16* __restrict__ bias_m,
                                                const void* res, int res_mode,
                                                const float* flag,
                                                void* C, int out_pf,
                                                int M, int N, int K, int relu,
                                                __bf16* swzbuf, int swz) {
    __shared__ __bf16 As[2][128 * 64];
    __shared__ __bf16 Bs[2][64 * 64];
    const int tid = threadIdx.x;
    int bx = blockIdx.x, by = blockIdx.y;
    xcd_remap(bx, by);
    const int m0 = by * 128;
    const int n0 = bx * 64;
    const int w = tid >> 6, lane = tid & 63;
    const int wr = (w >> 1) * 64, wc = (w & 1) * 32;
    const int lm = lane & 15, lg = lane >> 4;
    const int sw = lm & 7;
    const bool f32 = *flag > 0.5f;
    const bool rf32 = (res_mode == 2) && f32;
    const bool of32 = out_pf && f32;

    auto stage = [&](int buf, int k0) {
#pragma unroll
        for (int i = 0; i < 4; ++i) {
            int c = i * 256 + tid;
            int row = c >> 3, ch = c & 7;
            __builtin_amdgcn_global_load_lds(
                (const __attribute__((address_space(1))) void*)(A + (size_t)(m0 + row) * lda + k0 + ((ch ^ (row & 7)) << 3)),
                (__attribute__((address_space(3))) void*)(As[buf] + c * 8), 16, 0, 0);
        }
#pragma unroll
        for (int i = 0; i < 2; ++i) {
            int c = i * 256 + tid;
            int row = c >> 3, ch = c & 7;
            __builtin_amdgcn_global_load_lds(
                (const __attribute__((address_space(1))) void*)(Bt + (size_t)(n0 + row) * ldb + k0 + ((ch ^ (row & 7)) << 3)),
                (__attribute__((address_space(3))) void*)(Bs[buf] + c * 8), 16, 0, 0);
        }
    };

    f32x4 acc[4][2] = {};
    stage(0, 0);
    int cur = 0;
    for (int k0 = 0; k0 < K; k0 += 64) {
        if (k0 + 64 < K) {
            stage(cur ^ 1, k0 + 64);
            asm volatile("s_waitcnt vmcnt(6)" ::: "memory");  // tile-cur landed; next in flight
        } else {
            asm volatile("s_waitcnt vmcnt(0)" ::: "memory");
        }
        __builtin_amdgcn_s_barrier();
        bf16x8 a[4][2], b[2][2];
#pragma unroll
        for (int t = 0; t < 4; ++t)
#pragma unroll
            for (int h = 0; h < 2; ++h)
                a[t][h] = *(const bf16x8*)(As[cur] + (wr + t * 16 + lm) * 64 + ((((h << 2) | lg) ^ sw) << 3));
#pragma unroll
        for (int t = 0; t < 2; ++t)
#pragma unroll
            for (int h = 0; h < 2; ++h)
                b[t][h] = *(const bf16x8*)(Bs[cur] + (wc + t * 16 + lm) * 64 + ((((h << 2) | lg) ^ sw) << 3));
#pragma unroll
        for (int mt = 0; mt < 4; ++mt)
#pragma unroll
            for (int nt = 0; nt < 2; ++nt) {
                acc[mt][nt] = MFMA(a[mt][0], b[nt][0], acc[mt][nt]);
                acc[mt][nt] = MFMA(a[mt][1], b[nt][1], acc[mt][nt]);
            }
        asm volatile("s_waitcnt lgkmcnt(0)" ::: "memory");
        __builtin_amdgcn_sched_barrier(0);
        __builtin_amdgcn_s_barrier();
        cur ^= 1;
    }
#pragma unroll
    for (int mt = 0; mt < 4; ++mt) {
#pragma unroll
        for (int nt = 0; nt < 2; ++nt) {
            int col = n0 + wc + nt * 16 + lm;
            float bn = bias_n ? (float)bias_n[col] : 0.f;
#pragma unroll
            for (int r = 0; r < 4; ++r) {
                int row = m0 + wr + mt * 16 + lg * 4 + r;
                float vv = acc[mt][nt][r] + bn;
                if (bias_m) vv += (float)bias_m[row];
                if (relu) vv = fmaxf(vv, 0.f);
                if (swz == 2) {
                    swz_store(swzbuf, row >> 6, col >> 6, row & 63, col & 63, vv);
                } else {
                    size_t idx = (size_t)row * N + col;
                    if (res_mode) vv += rf32 ? ((const float*)res)[idx]
                                             : (float)(((const __bf16*)res)[idx]);
                    if (of32) ((float*)C)[idx] = vv;
                    else ((__bf16*)C)[idx] = (__bf16)vv;
                }
            }
        }
    }
}

// ---------------------------------------------------------------------------
// Attention v7: K=32 PV via kv-permutation. P B-frags are register concats of
// the two pk4 outputs of adjacent 16-chunks; V A-frags read the SAME four sh4s
// per lane as the K=16 version, re-paired. PV+rowsum: 20 MFMAs/tile (was 48).
// ---------------------------------------------------------------------------
__global__ __launch_bounds__(256) void attn_ks2(const __bf16* __restrict__ Q, int ldq,
                                                const __bf16* __restrict__ Kswz,
                                                const __bf16* __restrict__ Vswz,
                                                __bf16* __restrict__ Opart,
                                                float* __restrict__ lpart) {
    constexpr int S = 4096;
    __shared__ __bf16 lds[2 * 8192];   // [buf][K tile 4096 | V tile 4096]
    const int h = blockIdx.y, z = blockIdx.z;
    const int q0 = blockIdx.x * 128;
    const int tid = threadIdx.x, w = tid >> 6, lane = tid & 63;
    const int lm = lane & 15, lg = lane >> 4;

    const __bf16* gK = Kswz + (((size_t)h * 64 + z * 32) << 12);
    const __bf16* gV = Vswz + (((size_t)h * 64 + z * 32) << 12);

    // Q B-frags (n=lm is q), pre-scaled by 0.125*log2e.
    bf16x8 qf[2][2];
#pragma unroll
    for (int qc = 0; qc < 2; ++qc) {
        const __bf16* qp = Q + (size_t)(q0 + w * 32 + qc * 16 + lm) * ldq + h * 64;
        qf[qc][0] = *(const bf16x8*)(qp + lg * 8);
        qf[qc][1] = *(const bf16x8*)(qp + 32 + lg * 8);
#pragma unroll
        for (int hh = 0; hh < 2; ++hh) {
            bf16x8 t = qf[qc][hh];
#pragma unroll
            for (int i = 0; i < 8; ++i) t[i] = (__bf16)((float)t[i] * 0.1803368801f);
            qf[qc][hh] = t;
        }
    }
    bf16x8 ones8;
#pragma unroll
    for (int i = 0; i < 8; ++i) ones8[i] = (__bf16)1.f;

    f32x4 o_[4][2] = {};
    f32x4 l_[2] = {};

    auto issue = [&](int t) {
        __bf16* dK = lds + (t & 1) * 8192;
        __bf16* dV = dK + 4096;
        const __bf16* sK = gK + ((size_t)t << 12);
        const __bf16* sV = gV + ((size_t)t << 12);
#pragma unroll
        for (int i = 0; i < 2; ++i) {
            int c = i * 256 + tid;
            __builtin_amdgcn_global_load_lds(
                (const __attribute__((address_space(1))) void*)(sK + c * 8),
                (__attribute__((address_space(3))) void*)(dK + c * 8), 16, 0, 0);
            __builtin_amdgcn_global_load_lds(
                (const __attribute__((address_space(1))) void*)(sV + c * 8),
                (__attribute__((address_space(3))) void*)(dV + c * 8), 16, 0, 0);
        }
    };
    issue(0);
    for (int t = 0; t < 32; ++t) {
        __syncthreads();                 // drains DMA for tile t; closes prev compute
        if (t < 31) issue(t + 1);        // in flight across this tile's compute
        const __bf16* Kt = lds + (t & 1) * 8192;
        const __bf16* Vt = Kt + 4096;

        P8 pb[2][2];
#pragma unroll
        for (int mt = 0; mt < 4; ++mt) {
            int rr = mt * 16 + lm;
            const __bf16* kr = Kt + rr * 64;
            bf16x8 kf0 = *(const bf16x8*)(kr + ((lg ^ (rr & 7)) << 3));
            bf16x8 kf1 = *(const bf16x8*)(kr + (((4 + lg) ^ (rr & 7)) << 3));
#pragma unroll
            for (int qc = 0; qc < 2; ++qc) {
                f32x4 s = (f32x4){0.f, 0.f, 0.f, 0.f};
                s = MFMA(kf0, qf[qc][0], s);
                s = MFMA(kf1, qf[qc][1], s);
                sh4 e = pk4(EXP2(s[0]), EXP2(s[1]), EXP2(s[2]), EXP2(s[3]));
                if (mt & 1) pb[mt >> 1][qc].p.hi = e;
                else        pb[mt >> 1][qc].p.lo = e;
            }
        }
#pragma unroll
        for (int mtd = 0; mtd < 4; ++mtd) {
            int rr = mtd * 16 + lm;
            const __bf16* vr = Vt + rr * 64;
#pragma unroll
            for (int cp = 0; cp < 2; ++cp) {
                int cbase = cp * 4 + (lg >> 1);
                P8 va;
                va.p.lo = *(const sh4*)(vr + ((cbase ^ (rr & 7)) << 3) + (lg & 1) * 4);
                va.p.hi = *(const sh4*)(vr + (((cbase + 2) ^ (rr & 7)) << 3) + (lg & 1) * 4);
                bf16x8 vab = __builtin_bit_cast(bf16x8, va.v);
                o_[mtd][0] = MFMA(vab, __builtin_bit_cast(bf16x8, pb[cp][0].v), o_[mtd][0]);
                o_[mtd][1] = MFMA(vab, __builtin_bit_cast(bf16x8, pb[cp][1].v), o_[mtd][1]);
            }
        }
#pragma unroll
        for (int cp = 0; cp < 2; ++cp) {
            l_[0] = MFMA(ones8, __builtin_bit_cast(bf16x8, pb[cp][0].v), l_[0]);
            l_[1] = MFMA(ones8, __builtin_bit_cast(bf16x8, pb[cp][1].v), l_[1]);
        }
    }

    // Unnormalized O^T -> lds[128][72] (packed 8B stores) -> coalesced store.
    __syncthreads();
#pragma unroll
    for (int qc = 0; qc < 2; ++qc) {
#pragma unroll
        for (int mtd = 0; mtd < 4; ++mtd) {
            sh4 ov = pk4(o_[mtd][qc][0], o_[mtd][qc][1], o_[mtd][qc][2], o_[mtd][qc][3]);
            *(sh4*)(lds + (w * 32 + qc * 16 + lm) * 72 + mtd * 16 + lg * 4) = ov;
        }
        if (lg == 0)
            lpart[(size_t)(h * 2 + z) * S + q0 + w * 32 + qc * 16 + lm] = l_[qc][0];
    }
    __syncthreads();
    __bf16* Ob = Opart + (((size_t)(h * 2 + z) * S + q0) << 6);
    int row = tid >> 1, co = (tid & 1) * 32;
#pragma unroll
    for (int b = 0; b < 4; ++b)
        *(uint4*)(Ob + row * 64 + co + b * 8) = *(const uint4*)(lds + row * 72 + co + b * 8);
}

__global__ __launch_bounds__(256) void attn_comb(const __bf16* __restrict__ Opart,
                                                 const float* __restrict__ lpart,
                                                 __bf16* __restrict__ ctx) {
    constexpr int S = 4096;
#pragma unroll
    for (int it = 0; it < 4; ++it) {
        int task = blockIdx.x * 1024 + it * 256 + threadIdx.x;  // (q, c8)
        int q = task >> 7, c8 = task & 127, h = c8 >> 3, d8 = (c8 & 7) * 8;
        const __bf16* p0 = Opart + (((size_t)(h * 2 + 0) * S + q) << 6) + d8;
        const __bf16* p1 = Opart + (((size_t)(h * 2 + 1) * S + q) << 6) + d8;
        float inv = 1.f / (lpart[(size_t)(h * 2 + 0) * S + q] + lpart[(size_t)(h * 2 + 1) * S + q]);
        bf16x8 a = *(const bf16x8*)p0, b = *(const bf16x8*)p1, o;
#pragma unroll
        for (int i = 0; i < 8; ++i) o[i] = (__bf16)(((float)a[i] + (float)b[i]) * inv);
        *(bf16x8*)(ctx + (size_t)q * 1024 + c8 * 8) = o;
    }
}

// ---------------------------------------------------------------------------
// r6 attention (padded-LDS, no split) — fallback path only. Same K=32 PV.
// ---------------------------------------------------------------------------
__global__ __launch_bounds__(256) void attn_v3(const __bf16* __restrict__ Q, int ldq,
                                               const __bf16* __restrict__ Kg, int ldk,
                                               const __bf16* __restrict__ VT,
                                               __bf16* __restrict__ ctx) {
    constexpr int S = 4096, D = 1024, LDT = 72;
    __shared__ __bf16 lds[128 * LDT];
    __bf16* Kt = lds;
    __bf16* Vt = lds + 64 * LDT;
    const int h = blockIdx.y;
    const int q0 = blockIdx.x * 128;
    const int tid = threadIdx.x, w = tid >> 6, lane = tid & 63;
    const int lm = lane & 15, lg = lane >> 4;
    bf16x8 qf[2][2];
#pragma unroll
    for (int qc = 0; qc < 2; ++qc) {
        const __bf16* qp = Q + (size_t)(q0 + w * 32 + qc * 16 + lm) * ldq + h * 64;
        qf[qc][0] = *(const bf16x8*)(qp + lg * 8);
        qf[qc][1] = *(const bf16x8*)(qp + 32 + lg * 8);
#pragma unroll
        for (int hh = 0; hh < 2; ++hh) {
            bf16x8 t = qf[qc][hh];
#pragma unroll
            for (int i = 0; i < 8; ++i) t[i] = (__bf16)((float)t[i] * 0.1803368801f);
            qf[qc][hh] = t;
        }
    }
    bf16x8 ones8;
#pragma unroll
    for (int i = 0; i < 8; ++i) ones8[i] = (__bf16)1.f;
    f32x4 o_[4][2] = {};
    f32x4 l_[2] = {};
    for (int kt = 0; kt < S / 64; ++kt) {
        __syncthreads();
#pragma unroll
        for (int i = 0; i < 2; ++i) {
            int c = i * 256 + tid;
            int rr = c >> 3, cc = (c & 7) * 8;
            *(uint4*)(Kt + rr * LDT + cc) =
                *(const uint4*)(Kg + (size_t)(kt * 64 + rr) * ldk + h * 64 + cc);
            *(uint4*)(Vt + rr * LDT + cc) =
                *(const uint4*)(VT + (size_t)(h * 64 + rr) * S + kt * 64 + cc);
        }
        __syncthreads();
        P8 pb[2][2];
#pragma unroll
        for (int mt = 0; mt < 4; ++mt) {
            bf16x8 kf0 = *(const bf16x8*)(Kt + (mt * 16 + lm) * LDT + lg * 8);
            bf16x8 kf1 = *(const bf16x8*)(Kt + (mt * 16 + lm) * LDT + 32 + lg * 8);
#pragma unroll
            for (int qc = 0; qc < 2; ++qc) {
                f32x4 s = (f32x4){0.f, 0.f, 0.f, 0.f};
                s = MFMA(kf0, qf[qc][0], s);
                s = MFMA(kf1, qf[qc][1], s);
                sh4 e = pk4(EXP2(s[0]), EXP2(s[1]), EXP2(s[2]), EXP2(s[3]));
                if (mt & 1) pb[mt >> 1][qc].p.hi = e;
                else        pb[mt >> 1][qc].p.lo = e;
            }
        }
#pragma unroll
        for (int mtd = 0; mtd < 4; ++mtd) {
            const __bf16* vrow = Vt + (mtd * 16 + lm) * LDT;
#pragma unroll
            for (int cp = 0; cp < 2; ++cp) {
                P8 va;
                va.p.lo = *(const sh4*)(vrow + cp * 32 + lg * 4);
                va.p.hi = *(const sh4*)(vrow + cp * 32 + 16 + lg * 4);
                bf16x8 vab = __builtin_bit_cast(bf16x8, va.v);
                o_[mtd][0] = MFMA(vab, __builtin_bit_cast(bf16x8, pb[cp][0].v), o_[mtd][0]);
                o_[mtd][1] = MFMA(vab, __builtin_bit_cast(bf16x8, pb[cp][1].v), o_[mtd][1]);
            }
        }
#pragma unroll
        for (int cp = 0; cp < 2; ++cp) {
            l_[0] = MFMA(ones8, __builtin_bit_cast(bf16x8, pb[cp][0].v), l_[0]);
            l_[1] = MFMA(ones8, __builtin_bit_cast(bf16x8, pb[cp][1].v), l_[1]);
        }
    }
    __syncthreads();
    float inv[2] = {1.f / l_[0][0], 1.f / l_[1][0]};
#pragma unroll
    for (int qc = 0; qc < 2; ++qc)
#pragma unroll
        for (int mtd = 0; mtd < 4; ++mtd)
#pragma unroll
            for (int r = 0; r < 4; ++r)
                lds[(w * 32 + qc * 16 + lm) * LDT + mtd * 16 + lg * 4 + r] =
                    (__bf16)(o_[mtd][qc][r] * inv[qc]);
    __syncthreads();
    int row = tid >> 1, cb = (tid & 1) * 32;
#pragma unroll
    for (int b = 0; b < 4; ++b)
        *(uint4*)(ctx + (size_t)(q0 + row) * D + h * 64 + cb + b * 8) =
            *(const uint4*)(lds + row * LDT + cb + b * 8);
}

// ---------------------------------------------------------------------------
extern "C" void kernel_launch(void* const* d_in, const int* in_sizes, int n_in,
                              void* d_out, int out_size, void* d_ws, size_t ws_size,
                              hipStream_t stream) {
    const void* x    = d_in[0];
    const void* Wq   = d_in[1];
    const void* bq   = d_in[2];
    const void* Wk   = d_in[3];
    const void* bk   = d_in[4];
    const void* Wv   = d_in[5];
    const void* bv   = d_in[6];
    const void* Wo   = d_in[7];
    const void* bo   = d_in[8];
    const void* ln1a = d_in[9];
    const void* ln1b = d_in[10];
    const void* W1   = d_in[11];
    const void* b1   = d_in[12];
    const void* W2   = d_in[13];
    const void* b2   = d_in[14];
    const void* ln2a = d_in[15];
    const void* ln2b = d_in[16];

    constexpr size_t M1 = 1u << 20;
    __bf16* ws = (__bf16*)d_ws;
    float* flagF = (float*)ws;
    __bf16* bmir = ws;
    dim3 tb(32, 8);
    const bool big = ws_size >= (size_t)(32.25 * 2 * M1) + 4096;

    prep_k<<<1, 256, 0, stream>>>(Wq, flagF, bq, bk, bv, bo, b1, b2,
                                  ln1a, ln1b, ln2a, ln2b, bmir);

    if (big) {
        // peak 32.25M elems = 64.5 MB
        __bf16* WqT = ws + M1 / 4;
        __bf16* WkT = WqT + M1;
        __bf16* WvT = ws + 2 * M1 + M1 / 4;
        __bf16* WoT = ws + 3 * M1 + M1 / 4;
        __bf16* W2T = ws + M1 / 4;
        float* lpart = (float*)(ws + M1 / 4);
        __bf16* hb  = ws + 4 * M1 + M1 / 4;
        __bf16* h2  = hb;
        __bf16* QKb = ws + 8 * M1 + M1 / 4;
        __bf16* x2  = QKb;
        __bf16* W1T = ws + 12 * M1 + M1 / 4;
        __bf16* Kswz = ws + 16 * M1 + M1 / 4;
        __bf16* ctx  = Kswz;
        __bf16* Vswz = ws + 20 * M1 + M1 / 4;
        __bf16* Opart = ws + 24 * M1 + M1 / 4;
        __bf16* f1  = ws + 16 * M1 + M1 / 4;

        transpose4_cvt<<<dim3(32, 32, 4), tb, 0, stream>>>(Wq, Wk, Wv, Wo,
                                                           WqT, WkT, WvT, WoT, flagF);
        layernorm_k<<<1024, 256, 0, stream>>>(x, 1, flagF, hb, bmir + 10240, bmir + 10241);
        gemm_bt<<<dim3(16, 32), 256, 0, stream>>>(hb, 1024, WqT, 1024, bmir + 1024, nullptr,
                                                  nullptr, 0, flagF, QKb, 0, 4096, 2048, 1024, 0,
                                                  Kswz, 1);
        gemm_n64<<<dim3(64, 8), 256, 0, stream>>>(WvT, 1024, hb, 1024, nullptr, bmir + 3072,
                                                  nullptr, 0, flagF, nullptr, 0, 1024, 4096, 1024, 0,
                                                  Vswz, 2);
        attn_ks2<<<dim3(32, 16, 2), 256, 0, stream>>>(QKb, 2048, Kswz, Vswz, Opart, lpart);
        attn_comb<<<512, 256, 0, stream>>>(Opart, lpart, ctx);
        transpose_cvt<<<dim3(128, 32), tb, 0, stream>>>(W1, W1T, 1024, 4096, flagF);
        gemm_n64<<<dim3(16, 32), 256, 0, stream>>>(ctx, 1024, WoT, 1024, bmir + 4096, nullptr,
                                                   x, 2, flagF, x2, 0, 4096, 1024, 1024, 0,
                                                   nullptr, 0);
        transpose_cvt<<<dim3(32, 128), tb, 0, stream>>>(W2, W2T, 4096, 1024, flagF);
        layernorm_k<<<1024, 256, 0, stream>>>(x2, 0, flagF, h2, bmir + 10242, bmir + 10243);
        gemm_bt<<<dim3(32, 32), 256, 0, stream>>>(h2, 1024, W1T, 1024, bmir + 5120, nullptr,
                                                  nullptr, 0, flagF, f1, 0, 4096, 4096, 1024, 1,
                                                  nullptr, 0);
        gemm_n64<<<dim3(16, 32), 256, 0, stream>>>(f1, 4096, W2T, 4096, bmir + 9216, nullptr,
                                                   x2, 1, flagF, d_out, 1, 4096, 1024, 4096, 0,
                                                   nullptr, 0);
    } else {
        // chunked fallback (r6), peak 46.5 MB
        constexpr size_t Qn = 1u << 18;
        __bf16* WqT = ws + Qn;
        __bf16* WoT = WqT;
        __bf16* WkT = ws + 5 * Qn;
        __bf16* WvT = ws + 9 * Qn;
        __bf16* hb  = ws + 13 * Qn;
        __bf16* f1q = hb;
        __bf16* ctx = ws + 29 * Qn;
        __bf16* W2T = ctx;
        __bf16* QKb = ws + 45 * Qn;
        __bf16* x2  = QKb;
        __bf16* Kb  = ws + 61 * Qn;
        __bf16* h2  = Kb;
        __bf16* VTb = ws + 77 * Qn;
        __bf16* W1T = VTb;
        transpose_cvt<<<dim3(32, 32), tb, 0, stream>>>(Wq, WqT, 1024, 1024, flagF);
        transpose_cvt<<<dim3(32, 32), tb, 0, stream>>>(Wk, WkT, 1024, 1024, flagF);
        transpose_cvt<<<dim3(32, 32), tb, 0, stream>>>(Wv, WvT, 1024, 1024, flagF);
        layernorm_k<<<1024, 256, 0, stream>>>(x, 1, flagF, hb, bmir + 10240, bmir + 10241);
        gemm_bt<<<dim3(8, 32), 256, 0, stream>>>(hb, 1024, WqT, 1024, bmir + 1024, nullptr,
                                                 nullptr, 0, flagF, QKb, 0, 4096, 1024, 1024, 0,
                                                 nullptr, 0);
        gemm_bt<<<dim3(8, 32), 256, 0, stream>>>(hb, 1024, WkT, 1024, bmir + 2048, nullptr,
                                                 nullptr, 0, flagF, Kb, 0, 4096, 1024, 1024, 0,
                                                 nullptr, 0);
        gemm_n64<<<dim3(64, 8), 256, 0, stream>>>(WvT, 1024, hb, 1024, nullptr, bmir + 3072,
                                                  nullptr, 0, flagF, VTb, 0, 1024, 4096, 1024, 0,
                                                  nullptr, 0);
        attn_v3<<<dim3(32, 16), 256, 0, stream>>>(QKb, 1024, Kb, 1024, VTb, ctx);
        transpose_cvt<<<dim3(32, 32), tb, 0, stream>>>(Wo, WoT, 1024, 1024, flagF);
        gemm_n64<<<dim3(16, 32), 256, 0, stream>>>(ctx, 1024, WoT, 1024, bmir + 4096, nullptr,
                                                   x, 2, flagF, x2, 0, 4096, 1024, 1024, 0,
                                                   nullptr, 0);
        layernorm_k<<<1024, 256, 0, stream>>>(x2, 0, flagF, h2, bmir + 10242, bmir + 10243);
        transpose_cvt<<<dim3(128, 32), tb, 0, stream>>>(W1, W1T, 1024, 4096, flagF);
        transpose_cvt<<<dim3(32, 128), tb, 0, stream>>>(W2, W2T, 4096, 1024, flagF);
        for (int ck = 0; ck < 2; ++ck) {
            gemm_bt<<<dim3(16, 32), 256, 0, stream>>>(h2, 1024, W1T + (size_t)ck * 2048 * 1024,
                                                      1024, bmir + 5120 + ck * 2048, nullptr,
                                                      nullptr, 0, flagF, f1q, 0, 4096, 2048, 1024, 1,
                                                      nullptr, 0);
            gemm_n64<<<dim3(16, 32), 256, 0, stream>>>(f1q, 2048, W2T + ck * 2048, 4096,
                                                       ck == 0 ? bmir + 9216 : nullptr, nullptr,
                                                       x2, 1, flagF, ck == 1 ? d_out : (void*)x2,
                                                       ck == 1 ? 1 : 0, 4096, 1024, 2048, 0,
                                                       nullptr, 0);
        }
    }
}

// Round 8
// 461.898 us; speedup vs baseline: 1.0685x; 1.0289x over previous
//
#include <hip/hip_runtime.h>
#include <hip/hip_bf16.h>

typedef __attribute__((ext_vector_type(8))) __bf16 bf16x8;
typedef __attribute__((ext_vector_type(4))) float f32x4;
typedef __attribute__((ext_vector_type(4))) short sh4;
typedef __attribute__((ext_vector_type(8))) short sh8;

#define MFMA(a, b, c) __builtin_amdgcn_mfma_f32_16x16x32_bf16(a, b, c, 0, 0, 0)

#if __has_builtin(__builtin_amdgcn_exp2f)
#define EXP2(x) __builtin_amdgcn_exp2f(x)
#else
#define EXP2(x) exp2f(x)
#endif

// K=32 B-frag / V-frag pairing: slot s = lg*8 + c*4 + r <-> kv-row c*16 + lg*4 + r.
union P8 { struct { sh4 lo, hi; } p; sh8 v; };

__device__ __forceinline__ sh4 pk4(float a, float b, float c, float d) {
    __hip_bfloat162 lo = __float22bfloat162_rn(float2{a, b});
    __hip_bfloat162 hi = __float22bfloat162_rn(float2{c, d});
    union { struct { __hip_bfloat162 lo, hi; } p; sh4 s; } u;
    u.p.lo = lo; u.p.hi = hi;
    return u.s;
}

__device__ __forceinline__ float ldany(const void* p, size_t i, bool f32) {
    return f32 ? ((const float*)p)[i] : (float)(((const __bf16*)p)[i]);
}

// T1: XCD-aware bijective remap (chunked). Bijective when nwg%8==0; identity otherwise.
__device__ __forceinline__ void xcd_remap(int& bx, int& by) {
    int nx = gridDim.x;
    int nwg = nx * gridDim.y;
    int bid = by * nx + bx;
    if ((nwg & 7) == 0) {
        int id = (bid & 7) * (nwg >> 3) + (bid >> 3);
        bx = id % nx;
        by = id / nx;
    }
}

// ---------------------------------------------------------------------------
__global__ void prep_k(const void* wq, float* flag,
                       const void* bq, const void* bk, const void* bv, const void* bo,
                       const void* b1, const void* b2,
                       const void* l1a, const void* l1b, const void* l2a, const void* l2b,
                       __bf16* dst) {
    __shared__ float red[256];
    __shared__ float fls;
    int tid = threadIdx.x;
    const __bf16* p = (const __bf16*)wq;
    float mx = 0.f;
    for (int i = tid; i < 1024; i += 256) {
        float v = (float)p[i];
        if (v != v) mx = 2.f;
        v = fabsf(v);
        if (v > mx) mx = v;
    }
    red[tid] = mx;
    __syncthreads();
    for (int s = 128; s > 0; s >>= 1) {
        if (tid < s) red[tid] = fmaxf(red[tid], red[tid + s]);
        __syncthreads();
    }
    if (tid == 0) { fls = (red[0] > 1.0f) ? 1.f : 0.f; *flag = fls; }
    __syncthreads();
    bool f32 = fls > 0.5f;
    const void* srcs[10] = {bq, bk, bv, bo, b1, b2, l1a, l1b, l2a, l2b};
    const int offs[10] = {1024, 2048, 3072, 4096, 5120, 9216, 10240, 10241, 10242, 10243};
    const int ns[10]   = {1024, 1024, 1024, 1024, 4096, 1024, 1, 1, 1, 1};
    for (int t = 0; t < 10; ++t)
        for (int j = tid; j < ns[t]; j += blockDim.x)
            dst[offs[t] + j] = (__bf16)ldany(srcs[t], j, f32);
}

// ---------------------------------------------------------------------------
__device__ __forceinline__ void tr_body(const void* in, __bf16* out, int R, int C, bool f32,
                                        int bx, int by, int x, int y) {
    __shared__ __bf16 t[32][33];
    for (int i = 0; i < 32; i += 8)
        t[y + i][x] = (__bf16)ldany(in, (size_t)(by + y + i) * C + bx + x, f32);
    __syncthreads();
    for (int i = 0; i < 32; i += 8)
        out[(size_t)(bx + y + i) * R + by + x] = t[x][y + i];
}

__global__ void transpose_cvt(const void* in, __bf16* out, int R, int C, const float* flag) {
    tr_body(in, out, R, C, *flag > 0.5f, blockIdx.x * 32, blockIdx.y * 32,
            threadIdx.x, threadIdx.y);
}

__global__ void transpose4_cvt(const void* i0, const void* i1, const void* i2, const void* i3,
                               __bf16* o0, __bf16* o1, __bf16* o2, __bf16* o3,
                               const float* flag) {
    const void* in = blockIdx.z == 0 ? i0 : blockIdx.z == 1 ? i1 : blockIdx.z == 2 ? i2 : i3;
    __bf16* out = blockIdx.z == 0 ? o0 : blockIdx.z == 1 ? o1 : blockIdx.z == 2 ? o2 : o3;
    tr_body(in, out, 1024, 1024, *flag > 0.5f, blockIdx.x * 32, blockIdx.y * 32,
            threadIdx.x, threadIdx.y);
}

// ---------------------------------------------------------------------------
__global__ __launch_bounds__(256) void layernorm_k(const void* x, int xmode, const float* flag,
                                                   __bf16* out,
                                                   const __bf16* alpha, const __bf16* beta) {
    int row = blockIdx.x * 4 + (threadIdx.x >> 6);
    int lane = threadIdx.x & 63;
    bool f32 = xmode && (*flag > 0.5f);
    float v[16];
    if (f32) {
        const float4* xr = (const float4*)((const float*)x + (size_t)row * 1024 + lane * 16);
#pragma unroll
        for (int q = 0; q < 4; ++q) {
            float4 r = xr[q];
            v[q * 4 + 0] = r.x; v[q * 4 + 1] = r.y; v[q * 4 + 2] = r.z; v[q * 4 + 3] = r.w;
        }
    } else {
        const __bf16* xr = (const __bf16*)x + (size_t)row * 1024 + lane * 16;
        bf16x8 h0 = *(const bf16x8*)xr;
        bf16x8 h1 = *(const bf16x8*)(xr + 8);
#pragma unroll
        for (int i = 0; i < 8; ++i) { v[i] = (float)h0[i]; v[8 + i] = (float)h1[i]; }
    }
    float s = 0.f, ss = 0.f;
#pragma unroll
    for (int i = 0; i < 16; ++i) { s += v[i]; ss += v[i] * v[i]; }
#pragma unroll
    for (int o = 1; o < 64; o <<= 1) { s += __shfl_xor(s, o); ss += __shfl_xor(ss, o); }
    float mu = s * (1.f / 1024.f);
    float var = (ss - 1024.f * mu * mu) * (1.f / 1023.f);
    float inv = 1.f / (sqrtf(var) + 1e-6f);
    float al = (float)alpha[0], be = (float)beta[0];
    bf16x8 o0, o1;
#pragma unroll
    for (int i = 0; i < 8; ++i) {
        o0[i] = (__bf16)((v[i] - mu) * inv * al + be);
        o1[i] = (__bf16)((v[8 + i] - mu) * inv * al + be);
    }
    __bf16* orow = out + (size_t)row * 1024;
    *(bf16x8*)(orow + lane * 16) = o0;
    *(bf16x8*)(orow + lane * 16 + 8) = o1;
}

// Swizzled-tile store helpers: 64x64 tiles, chunk (8 halves) XOR'd by row&7.
__device__ __forceinline__ void swz_store(__bf16* buf, int hh, int ktt, int rr2, int cc2,
                                          float v) {
    size_t off = (((size_t)hh * 64 + ktt) << 12) + rr2 * 64 +
                 (((cc2 >> 3) ^ (rr2 & 7)) << 3) + (cc2 & 7);
    buf[off] = (__bf16)v;
}

// ---------------------------------------------------------------------------
// GEMM 128x128 (256 thr), double-buffered, counted vmcnt, T1 remap.
// ---------------------------------------------------------------------------
__global__ __launch_bounds__(256) void gemm_bt(const __bf16* __restrict__ A, int lda,
                                               const __bf16* __restrict__ Bt, int ldb,
                                               const __bf16* __restrict__ bias_n,
                                               const __bf16* __restrict__ bias_m,
                                               const void* res, int res_mode,
                                               const float* flag,
                                               void* C, int out_pf,
                                               int M, int N, int K, int relu,
                                               __bf16* swzbuf, int swz) {
    __shared__ __bf16 As[2][128 * 32];
    __shared__ __bf16 Bs[2][128 * 32];
    const int tid = threadIdx.x;
    int bx = blockIdx.x, by = blockIdx.y;
    xcd_remap(bx, by);
    const int m0 = by * 128;
    const int n0 = bx * 128;
    const int w = tid >> 6, lane = tid & 63;
    const int wr = (w >> 1) * 64, wc = (w & 1) * 64;
    const int lm = lane & 15, lg = lane >> 4;
    const bool f32 = *flag > 0.5f;
    const bool rf32 = (res_mode == 2) && f32;
    const bool of32 = out_pf && f32;

    auto stage = [&](int buf, int k0) {
#pragma unroll
        for (int i = 0; i < 2; ++i) {
            int c = i * 256 + tid;
            int row = c >> 2, kk = (c & 3) * 8;
            __builtin_amdgcn_global_load_lds(
                (const __attribute__((address_space(1))) void*)(A + (size_t)(m0 + row) * lda + k0 + kk),
                (__attribute__((address_space(3))) void*)(As[buf] + c * 8), 16, 0, 0);
            __builtin_amdgcn_global_load_lds(
                (const __attribute__((address_space(1))) void*)(Bt + (size_t)(n0 + row) * ldb + k0 + kk),
                (__attribute__((address_space(3))) void*)(Bs[buf] + c * 8), 16, 0, 0);
        }
    };

    f32x4 acc[4][4] = {};
    stage(0, 0);
    int cur = 0;
    for (int k0 = 0; k0 < K; k0 += 32) {
        if (k0 + 32 < K) {
            stage(cur ^ 1, k0 + 32);
            asm volatile("s_waitcnt vmcnt(4)" ::: "memory");
        } else {
            asm volatile("s_waitcnt vmcnt(0)" ::: "memory");
        }
        __builtin_amdgcn_s_barrier();
        bf16x8 a[4], b[4];
#pragma unroll
        for (int t = 0; t < 4; ++t)
            a[t] = *(const bf16x8*)(As[cur] + (wr + t * 16 + lm) * 32 + lg * 8);
#pragma unroll
        for (int t = 0; t < 4; ++t)
            b[t] = *(const bf16x8*)(Bs[cur] + (wc + t * 16 + lm) * 32 + lg * 8);
#pragma unroll
        for (int mt = 0; mt < 4; ++mt)
#pragma unroll
            for (int nt = 0; nt < 4; ++nt)
                acc[mt][nt] = MFMA(a[mt], b[nt], acc[mt][nt]);
        asm volatile("s_waitcnt lgkmcnt(0)" ::: "memory");
        __builtin_amdgcn_sched_barrier(0);
        __builtin_amdgcn_s_barrier();
        cur ^= 1;
    }
#pragma unroll
    for (int mt = 0; mt < 4; ++mt) {
#pragma unroll
        for (int nt = 0; nt < 4; ++nt) {
            int col = n0 + wc + nt * 16 + lm;
            float bn = bias_n ? (float)bias_n[col] : 0.f;
#pragma unroll
            for (int r = 0; r < 4; ++r) {
                int row = m0 + wr + mt * 16 + lg * 4 + r;
                float vv = acc[mt][nt][r] + bn;
                if (bias_m) vv += (float)bias_m[row];
                if (relu) vv = fmaxf(vv, 0.f);
                if (swz == 1 && col >= 1024) {
                    swz_store(swzbuf, (col - 1024) >> 6, row >> 6, row & 63, (col - 1024) & 63, vv);
                } else if (swz == 2) {
                    swz_store(swzbuf, row >> 6, col >> 6, row & 63, col & 63, vv);
                } else {
                    size_t idx = (size_t)row * N + col;
                    if (res_mode) vv += rf32 ? ((const float*)res)[idx]
                                             : (float)(((const __bf16*)res)[idx]);
                    if (of32) ((float*)C)[idx] = vv;
                    else ((__bf16*)C)[idx] = (__bf16)vv;
                }
            }
        }
    }
}

// ---------------------------------------------------------------------------
// GEMM 128x64 (256 thr), BK=64, double-buffered, counted vmcnt(6), T1 remap.
// ---------------------------------------------------------------------------
__global__ __launch_bounds__(256) void gemm_n64(const __bf16* __restrict__ A, int lda,
                                                const __bf16* __restrict__ Bt, int ldb,
                                                const __bf16* __restrict__ bias_n,
                                                const __bf16* __restrict__ bias_m,
                                                const void* res, int res_mode,
                                                const float* flag,
                                                void* C, int out_pf,
                                                int M, int N, int K, int relu,
                                                __bf16* swzbuf, int swz) {
    __shared__ __bf16 As[2][128 * 64];
    __shared__ __bf16 Bs[2][64 * 64];
    const int tid = threadIdx.x;
    int bx = blockIdx.x, by = blockIdx.y;
    xcd_remap(bx, by);
    const int m0 = by * 128;
    const int n0 = bx * 64;
    const int w = tid >> 6, lane = tid & 63;
    const int wr = (w >> 1) * 64, wc = (w & 1) * 32;
    const int lm = lane & 15, lg = lane >> 4;
    const int sw = lm & 7;
    const bool f32 = *flag > 0.5f;
    const bool rf32 = (res_mode == 2) && f32;
    const bool of32 = out_pf && f32;

    auto stage = [&](int buf, int k0) {
#pragma unroll
        for (int i = 0; i < 4; ++i) {
            int c = i * 256 + tid;
            int row = c >> 3, ch = c & 7;
            __builtin_amdgcn_global_load_lds(
                (const __attribute__((address_space(1))) void*)(A + (size_t)(m0 + row) * lda + k0 + ((ch ^ (row & 7)) << 3)),
                (__attribute__((address_space(3))) void*)(As[buf] + c * 8), 16, 0, 0);
        }
#pragma unroll
        for (int i = 0; i < 2; ++i) {
            int c = i * 256 + tid;
            int row = c >> 3, ch = c & 7;
            __builtin_amdgcn_global_load_lds(
                (const __attribute__((address_space(1))) void*)(Bt + (size_t)(n0 + row) * ldb + k0 + ((ch ^ (row & 7)) << 3)),
                (__attribute__((address_space(3))) void*)(Bs[buf] + c * 8), 16, 0, 0);
        }
    };

    f32x4 acc[4][2] = {};
    stage(0, 0);
    int cur = 0;
    for (int k0 = 0; k0 < K; k0 += 64) {
        if (k0 + 64 < K) {
            stage(cur ^ 1, k0 + 64);
            asm volatile("s_waitcnt vmcnt(6)" ::: "memory");
        } else {
            asm volatile("s_waitcnt vmcnt(0)" ::: "memory");
        }
        __builtin_amdgcn_s_barrier();
        bf16x8 a[4][2], b[2][2];
#pragma unroll
        for (int t = 0; t < 4; ++t)
#pragma unroll
            for (int h = 0; h < 2; ++h)
                a[t][h] = *(const bf16x8*)(As[cur] + (wr + t * 16 + lm) * 64 + ((((h << 2) | lg) ^ sw) << 3));
#pragma unroll
        for (int t = 0; t < 2; ++t)
#pragma unroll
            for (int h = 0; h < 2; ++h)
                b[t][h] = *(const bf16x8*)(Bs[cur] + (wc + t * 16 + lm) * 64 + ((((h << 2) | lg) ^ sw) << 3));
#pragma unroll
        for (int mt = 0; mt < 4; ++mt)
#pragma unroll
            for (int nt = 0; nt < 2; ++nt) {
                acc[mt][nt] = MFMA(a[mt][0], b[nt][0], acc[mt][nt]);
                acc[mt][nt] = MFMA(a[mt][1], b[nt][1], acc[mt][nt]);
            }
        asm volatile("s_waitcnt lgkmcnt(0)" ::: "memory");
        __builtin_amdgcn_sched_barrier(0);
        __builtin_amdgcn_s_barrier();
        cur ^= 1;
    }
#pragma unroll
    for (int mt = 0; mt < 4; ++mt) {
#pragma unroll
        for (int nt = 0; nt < 2; ++nt) {
            int col = n0 + wc + nt * 16 + lm;
            float bn = bias_n ? (float)bias_n[col] : 0.f;
#pragma unroll
            for (int r = 0; r < 4; ++r) {
                int row = m0 + wr + mt * 16 + lg * 4 + r;
                float vv = acc[mt][nt][r] + bn;
                if (bias_m) vv += (float)bias_m[row];
                if (relu) vv = fmaxf(vv, 0.f);
                if (swz == 2) {
                    swz_store(swzbuf, row >> 6, col >> 6, row & 63, col & 63, vv);
                } else {
                    size_t idx = (size_t)row * N + col;
                    if (res_mode) vv += rf32 ? ((const float*)res)[idx]
                                             : (float)(((const __bf16*)res)[idx]);
                    if (of32) ((float*)C)[idx] = vv;
                    else ((__bf16*)C)[idx] = (__bf16)vv;
                }
            }
        }
    }
}

// ---------------------------------------------------------------------------
// GEMM 256x256, 8-phase schedule (T3+T4+T2+T5+T1). 512 thr = 8 waves (2Mx4N),
// BK=64, 2 K-tiles/iter, 128 KiB LDS (2 dbuf x 2 halves x [128][64] x A,B).
// Per phase: {ds_read subtile || stage half-tiles -> barrier -> lgkmcnt(0)
// -> setprio(1) 16 MFMA setprio(0) -> barrier}. Staging targets only
// barrier-certified dead dbuf regions: dbuf1 (next odd tile) at ph0/ph1,
// dbuf0 (next even tile) at ph4/ph5; vmcnt(0) only at ph3/ph7 where waited
// loads are 2-3 phases (~600-900cyc) old. Chunk-XOR swizzle identical to
// gemm_n64 (pre-swizzled global src, linear LDS dest, swizzled ds_read).
// Requires K % 128 == 0, M % 256 == 0, N % 256 == 0. bf16 in/out.
// ---------------------------------------------------------------------------
__global__ __launch_bounds__(512) void gemm_8ph(const __bf16* __restrict__ A, int lda,
                                                const __bf16* __restrict__ Bt, int ldb,
                                                const __bf16* __restrict__ bias_n,
                                                __bf16* __restrict__ C,
                                                int M, int N, int K, int relu) {
    __shared__ __bf16 As8[4 * 8192];   // [dbuf][half][128][64] = 64 KiB
    __shared__ __bf16 Bs8[4 * 8192];   // 64 KiB
    const int tid = threadIdx.x;
    int bx = blockIdx.x, by = blockIdx.y;
    xcd_remap(bx, by);
    const int m0 = by * 256, n0 = bx * 256;
    const int w = tid >> 6, lane = tid & 63;
    const int lm = lane & 15, lg = lane >> 4;
    const int wm = w >> 2, wn = w & 3;     // wave grid 2(M) x 4(N)
    const int sw = lm & 7;

    // Stage both halves (256 rows) of one operand K-tile: 4 load-rounds.
    auto stageA = [&](int d, int k0) {
#pragma unroll
        for (int i = 0; i < 4; ++i) {
            int c = i * 512 + tid;             // 0..2047
            int row = c >> 3, ch = c & 7;      // row 0..255
            __builtin_amdgcn_global_load_lds(
                (const __attribute__((address_space(1))) void*)(A + (size_t)(m0 + row) * lda + k0 + ((ch ^ (row & 7)) << 3)),
                (__attribute__((address_space(3))) void*)(As8 + d * 2 * 8192 + c * 8), 16, 0, 0);
        }
    };
    auto stageB = [&](int d, int k0) {
#pragma unroll
        for (int i = 0; i < 4; ++i) {
            int c = i * 512 + tid;
            int row = c >> 3, ch = c & 7;
            __builtin_amdgcn_global_load_lds(
                (const __attribute__((address_space(1))) void*)(Bt + (size_t)(n0 + row) * ldb + k0 + ((ch ^ (row & 7)) << 3)),
                (__attribute__((address_space(3))) void*)(Bs8 + d * 2 * 8192 + c * 8), 16, 0, 0);
        }
    };

    f32x4 acc[8][4] = {};
    const int NT = K >> 6, NI = NT >> 1;

    stageA(0, 0);
    stageB(0, 0);
    asm volatile("s_waitcnt vmcnt(0)" ::: "memory");
    __builtin_amdgcn_s_barrier();

    for (int i = 0; i < NI; ++i) {
        const int k1 = (2 * i + 1) * 64;       // dbuf1 tile (consumed ph4-7)
        const int k2 = (2 * i + 2) * 64;       // next dbuf0 tile
        const bool has2 = k2 < K;
#pragma unroll
        for (int p4 = 0; p4 < 2; ++p4) {
            const __bf16* Ab = As8 + (p4 * 2 + wm) * 8192;
            const __bf16* Bb = Bs8 + (p4 * 2 + (wn >> 1)) * 8192;
            bf16x8 breg[2][4];
#pragma unroll
            for (int kk = 0; kk < 2; ++kk) {
#pragma unroll
                for (int mh = 0; mh < 2; ++mh) {
                    const int ph = p4 * 4 + kk * 2 + mh;
                    // --- ds_read subtile for this phase ---
                    bf16x8 areg[4];
#pragma unroll
                    for (int q = 0; q < 4; ++q) {
                        int rr = (mh * 4 + q) * 16 + lm;
                        areg[q] = *(const bf16x8*)(Ab + rr * 64 + (((kk * 4 + lg) ^ sw) << 3));
                    }
                    if (mh == 0) {
#pragma unroll
                        for (int nt = 0; nt < 4; ++nt) {
                            int rr = (wn & 1) * 64 + nt * 16 + lm;
                            breg[kk][nt] = *(const bf16x8*)(Bb + rr * 64 + (((kk * 4 + lg) ^ sw) << 3));
                        }
                    }
                    // --- stage into the dead dbuf region ---
                    if (ph == 0) stageA(1, k1);
                    else if (ph == 1) stageB(1, k1);
                    else if (ph == 4) { if (has2) stageA(0, k2); }
                    else if (ph == 5) { if (has2) stageB(0, k2); }
                    __builtin_amdgcn_s_barrier();
                    asm volatile("s_waitcnt lgkmcnt(0)" ::: "memory");
                    __builtin_amdgcn_sched_barrier(0);
                    __builtin_amdgcn_s_setprio(1);
#pragma unroll
                    for (int q = 0; q < 4; ++q)
#pragma unroll
                        for (int nt = 0; nt < 4; ++nt)
                            acc[mh * 4 + q][nt] = MFMA(areg[q], breg[kk][nt], acc[mh * 4 + q][nt]);
                    __builtin_amdgcn_s_setprio(0);
                    if (ph == 3 || ph == 7)
                        asm volatile("s_waitcnt vmcnt(0)" ::: "memory");
                    __builtin_amdgcn_s_barrier();
                }
            }
        }
    }
#pragma unroll
    for (int mt = 0; mt < 8; ++mt) {
#pragma unroll
        for (int nt = 0; nt < 4; ++nt) {
            int col = n0 + wn * 64 + nt * 16 + lm;
            float bn = bias_n ? (float)bias_n[col] : 0.f;
#pragma unroll
            for (int r = 0; r < 4; ++r) {
                int row = m0 + wm * 128 + mt * 16 + lg * 4 + r;
                float vv = acc[mt][nt][r] + bn;
                if (relu) vv = fmaxf(vv, 0.f);
                C[(size_t)row * N + col] = (__bf16)vv;
            }
        }
    }
}

// ---------------------------------------------------------------------------
// Attention v7: K=32 PV via kv-permutation.
// ---------------------------------------------------------------------------
__global__ __launch_bounds__(256) void attn_ks2(const __bf16* __restrict__ Q, int ldq,
                                                const __bf16* __restrict__ Kswz,
                                                const __bf16* __restrict__ Vswz,
                                                __bf16* __restrict__ Opart,
                                                float* __restrict__ lpart) {
    constexpr int S = 4096;
    __shared__ __bf16 lds[2 * 8192];
    const int h = blockIdx.y, z = blockIdx.z;
    const int q0 = blockIdx.x * 128;
    const int tid = threadIdx.x, w = tid >> 6, lane = tid & 63;
    const int lm = lane & 15, lg = lane >> 4;

    const __bf16* gK = Kswz + (((size_t)h * 64 + z * 32) << 12);
    const __bf16* gV = Vswz + (((size_t)h * 64 + z * 32) << 12);

    bf16x8 qf[2][2];
#pragma unroll
    for (int qc = 0; qc < 2; ++qc) {
        const __bf16* qp = Q + (size_t)(q0 + w * 32 + qc * 16 + lm) * ldq + h * 64;
        qf[qc][0] = *(const bf16x8*)(qp + lg * 8);
        qf[qc][1] = *(const bf16x8*)(qp + 32 + lg * 8);
#pragma unroll
        for (int hh = 0; hh < 2; ++hh) {
            bf16x8 t = qf[qc][hh];
#pragma unroll
            for (int i = 0; i < 8; ++i) t[i] = (__bf16)((float)t[i] * 0.1803368801f);
            qf[qc][hh] = t;
        }
    }
    bf16x8 ones8;
#pragma unroll
    for (int i = 0; i < 8; ++i) ones8[i] = (__bf16)1.f;

    f32x4 o_[4][2] = {};
    f32x4 l_[2] = {};

    auto issue = [&](int t) {
        __bf16* dK = lds + (t & 1) * 8192;
        __bf16* dV = dK + 4096;
        const __bf16* sK = gK + ((size_t)t << 12);
        const __bf16* sV = gV + ((size_t)t << 12);
#pragma unroll
        for (int i = 0; i < 2; ++i) {
            int c = i * 256 + tid;
            __builtin_amdgcn_global_load_lds(
                (const __attribute__((address_space(1))) void*)(sK + c * 8),
                (__attribute__((address_space(3))) void*)(dK + c * 8), 16, 0, 0);
            __builtin_amdgcn_global_load_lds(
                (const __attribute__((address_space(1))) void*)(sV + c * 8),
                (__attribute__((address_space(3))) void*)(dV + c * 8), 16, 0, 0);
        }
    };
    issue(0);
    for (int t = 0; t < 32; ++t) {
        __syncthreads();
        if (t < 31) issue(t + 1);
        const __bf16* Kt = lds + (t & 1) * 8192;
        const __bf16* Vt = Kt + 4096;

        P8 pb[2][2];
#pragma unroll
        for (int mt = 0; mt < 4; ++mt) {
            int rr = mt * 16 + lm;
            const __bf16* kr = Kt + rr * 64;
            bf16x8 kf0 = *(const bf16x8*)(kr + ((lg ^ (rr & 7)) << 3));
            bf16x8 kf1 = *(const bf16x8*)(kr + (((4 + lg) ^ (rr & 7)) << 3));
#pragma unroll
            for (int qc = 0; qc < 2; ++qc) {
                f32x4 s = (f32x4){0.f, 0.f, 0.f, 0.f};
                s = MFMA(kf0, qf[qc][0], s);
                s = MFMA(kf1, qf[qc][1], s);
                sh4 e = pk4(EXP2(s[0]), EXP2(s[1]), EXP2(s[2]), EXP2(s[3]));
                if (mt & 1) pb[mt >> 1][qc].p.hi = e;
                else        pb[mt >> 1][qc].p.lo = e;
            }
        }
#pragma unroll
        for (int mtd = 0; mtd < 4; ++mtd) {
            int rr = mtd * 16 + lm;
            const __bf16* vr = Vt + rr * 64;
#pragma unroll
            for (int cp = 0; cp < 2; ++cp) {
                int cbase = cp * 4 + (lg >> 1);
                P8 va;
                va.p.lo = *(const sh4*)(vr + ((cbase ^ (rr & 7)) << 3) + (lg & 1) * 4);
                va.p.hi = *(const sh4*)(vr + (((cbase + 2) ^ (rr & 7)) << 3) + (lg & 1) * 4);
                bf16x8 vab = __builtin_bit_cast(bf16x8, va.v);
                o_[mtd][0] = MFMA(vab, __builtin_bit_cast(bf16x8, pb[cp][0].v), o_[mtd][0]);
                o_[mtd][1] = MFMA(vab, __builtin_bit_cast(bf16x8, pb[cp][1].v), o_[mtd][1]);
            }
        }
#pragma unroll
        for (int cp = 0; cp < 2; ++cp) {
            l_[0] = MFMA(ones8, __builtin_bit_cast(bf16x8, pb[cp][0].v), l_[0]);
            l_[1] = MFMA(ones8, __builtin_bit_cast(bf16x8, pb[cp][1].v), l_[1]);
        }
    }

    __syncthreads();
#pragma unroll
    for (int qc = 0; qc < 2; ++qc) {
#pragma unroll
        for (int mtd = 0; mtd < 4; ++mtd) {
            sh4 ov = pk4(o_[mtd][qc][0], o_[mtd][qc][1], o_[mtd][qc][2], o_[mtd][qc][3]);
            *(sh4*)(lds + (w * 32 + qc * 16 + lm) * 72 + mtd * 16 + lg * 4) = ov;
        }
        if (lg == 0)
            lpart[(size_t)(h * 2 + z) * S + q0 + w * 32 + qc * 16 + lm] = l_[qc][0];
    }
    __syncthreads();
    __bf16* Ob = Opart + (((size_t)(h * 2 + z) * S + q0) << 6);
    int row = tid >> 1, co = (tid & 1) * 32;
#pragma unroll
    for (int b = 0; b < 4; ++b)
        *(uint4*)(Ob + row * 64 + co + b * 8) = *(const uint4*)(lds + row * 72 + co + b * 8);
}

__global__ __launch_bounds__(256) void attn_comb(const __bf16* __restrict__ Opart,
                                                 const float* __restrict__ lpart,
                                                 __bf16* __restrict__ ctx) {
    constexpr int S = 4096;
#pragma unroll
    for (int it = 0; it < 4; ++it) {
        int task = blockIdx.x * 1024 + it * 256 + threadIdx.x;
        int q = task >> 7, c8 = task & 127, h = c8 >> 3, d8 = (c8 & 7) * 8;
        const __bf16* p0 = Opart + (((size_t)(h * 2 + 0) * S + q) << 6) + d8;
        const __bf16* p1 = Opart + (((size_t)(h * 2 + 1) * S + q) << 6) + d8;
        float inv = 1.f / (lpart[(size_t)(h * 2 + 0) * S + q] + lpart[(size_t)(h * 2 + 1) * S + q]);
        bf16x8 a = *(const bf16x8*)p0, b = *(const bf16x8*)p1, o;
#pragma unroll
        for (int i = 0; i < 8; ++i) o[i] = (__bf16)(((float)a[i] + (float)b[i]) * inv);
        *(bf16x8*)(ctx + (size_t)q * 1024 + c8 * 8) = o;
    }
}

// ---------------------------------------------------------------------------
// r6 attention — fallback path only.
// ---------------------------------------------------------------------------
__global__ __launch_bounds__(256) void attn_v3(const __bf16* __restrict__ Q, int ldq,
                                               const __bf16* __restrict__ Kg, int ldk,
                                               const __bf16* __restrict__ VT,
                                               __bf16* __restrict__ ctx) {
    constexpr int S = 4096, D = 1024, LDT = 72;
    __shared__ __bf16 lds[128 * LDT];
    __bf16* Kt = lds;
    __bf16* Vt = lds + 64 * LDT;
    const int h = blockIdx.y;
    const int q0 = blockIdx.x * 128;
    const int tid = threadIdx.x, w = tid >> 6, lane = tid & 63;
    const int lm = lane & 15, lg = lane >> 4;
    bf16x8 qf[2][2];
#pragma unroll
    for (int qc = 0; qc < 2; ++qc) {
        const __bf16* qp = Q + (size_t)(q0 + w * 32 + qc * 16 + lm) * ldq + h * 64;
        qf[qc][0] = *(const bf16x8*)(qp + lg * 8);
        qf[qc][1] = *(const bf16x8*)(qp + 32 + lg * 8);
#pragma unroll
        for (int hh = 0; hh < 2; ++hh) {
            bf16x8 t = qf[qc][hh];
#pragma unroll
            for (int i = 0; i < 8; ++i) t[i] = (__bf16)((float)t[i] * 0.1803368801f);
            qf[qc][hh] = t;
        }
    }
    bf16x8 ones8;
#pragma unroll
    for (int i = 0; i < 8; ++i) ones8[i] = (__bf16)1.f;
    f32x4 o_[4][2] = {};
    f32x4 l_[2] = {};
    for (int kt = 0; kt < S / 64; ++kt) {
        __syncthreads();
#pragma unroll
        for (int i = 0; i < 2; ++i) {
            int c = i * 256 + tid;
            int rr = c >> 3, cc = (c & 7) * 8;
            *(uint4*)(Kt + rr * LDT + cc) =
                *(const uint4*)(Kg + (size_t)(kt * 64 + rr) * ldk + h * 64 + cc);
            *(uint4*)(Vt + rr * LDT + cc) =
                *(const uint4*)(VT + (size_t)(h * 64 + rr) * S + kt * 64 + cc);
        }
        __syncthreads();
        P8 pb[2][2];
#pragma unroll
        for (int mt = 0; mt < 4; ++mt) {
            bf16x8 kf0 = *(const bf16x8*)(Kt + (mt * 16 + lm) * LDT + lg * 8);
            bf16x8 kf1 = *(const bf16x8*)(Kt + (mt * 16 + lm) * LDT + 32 + lg * 8);
#pragma unroll
            for (int qc = 0; qc < 2; ++qc) {
                f32x4 s = (f32x4){0.f, 0.f, 0.f, 0.f};
                s = MFMA(kf0, qf[qc][0], s);
                s = MFMA(kf1, qf[qc][1], s);
                sh4 e = pk4(EXP2(s[0]), EXP2(s[1]), EXP2(s[2]), EXP2(s[3]));
                if (mt & 1) pb[mt >> 1][qc].p.hi = e;
                else        pb[mt >> 1][qc].p.lo = e;
            }
        }
#pragma unroll
        for (int mtd = 0; mtd < 4; ++mtd) {
            const __bf16* vrow = Vt + (mtd * 16 + lm) * LDT;
#pragma unroll
            for (int cp = 0; cp < 2; ++cp) {
                P8 va;
                va.p.lo = *(const sh4*)(vrow + cp * 32 + lg * 4);
                va.p.hi = *(const sh4*)(vrow + cp * 32 + 16 + lg * 4);
                bf16x8 vab = __builtin_bit_cast(bf16x8, va.v);
                o_[mtd][0] = MFMA(vab, __builtin_bit_cast(bf16x8, pb[cp][0].v), o_[mtd][0]);
                o_[mtd][1] = MFMA(vab, __builtin_bit_cast(bf16x8, pb[cp][1].v), o_[mtd][1]);
            }
        }
#pragma unroll
        for (int cp = 0; cp < 2; ++cp) {
            l_[0] = MFMA(ones8, __builtin_bit_cast(bf16x8, pb[cp][0].v), l_[0]);
            l_[1] = MFMA(ones8, __builtin_bit_cast(bf16x8, pb[cp][1].v), l_[1]);
        }
    }
    __syncthreads();
    float inv[2] = {1.f / l_[0][0], 1.f / l_[1][0]};
#pragma unroll
    for (int qc = 0; qc < 2; ++qc)
#pragma unroll
        for (int mtd = 0; mtd < 4; ++mtd)
#pragma unroll
            for (int r = 0; r < 4; ++r)
                lds[(w * 32 + qc * 16 + lm) * LDT + mtd * 16 + lg * 4 + r] =
                    (__bf16)(o_[mtd][qc][r] * inv[qc]);
    __syncthreads();
    int row = tid >> 1, cb = (tid & 1) * 32;
#pragma unroll
    for (int b = 0; b < 4; ++b)
        *(uint4*)(ctx + (size_t)(q0 + row) * D + h * 64 + cb + b * 8) =
            *(const uint4*)(lds + row * LDT + cb + b * 8);
}

// ---------------------------------------------------------------------------
extern "C" void kernel_launch(void* const* d_in, const int* in_sizes, int n_in,
                              void* d_out, int out_size, void* d_ws, size_t ws_size,
                              hipStream_t stream) {
    const void* x    = d_in[0];
    const void* Wq   = d_in[1];
    const void* bq   = d_in[2];
    const void* Wk   = d_in[3];
    const void* bk   = d_in[4];
    const void* Wv   = d_in[5];
    const void* bv   = d_in[6];
    const void* Wo   = d_in[7];
    const void* bo   = d_in[8];
    const void* ln1a = d_in[9];
    const void* ln1b = d_in[10];
    const void* W1   = d_in[11];
    const void* b1   = d_in[12];
    const void* W2   = d_in[13];
    const void* b2   = d_in[14];
    const void* ln2a = d_in[15];
    const void* ln2b = d_in[16];

    constexpr size_t M1 = 1u << 20;
    __bf16* ws = (__bf16*)d_ws;
    float* flagF = (float*)ws;
    __bf16* bmir = ws;
    dim3 tb(32, 8);
    const bool big = ws_size >= (size_t)(32.25 * 2 * M1) + 4096;

    prep_k<<<1, 256, 0, stream>>>(Wq, flagF, bq, bk, bv, bo, b1, b2,
                                  ln1a, ln1b, ln2a, ln2b, bmir);

    if (big) {
        __bf16* WqT = ws + M1 / 4;
        __bf16* WkT = WqT + M1;
        __bf16* WvT = ws + 2 * M1 + M1 / 4;
        __bf16* WoT = ws + 3 * M1 + M1 / 4;
        __bf16* W2T = ws + M1 / 4;
        float* lpart = (float*)(ws + M1 / 4);
        __bf16* hb  = ws + 4 * M1 + M1 / 4;
        __bf16* h2  = hb;
        __bf16* QKb = ws + 8 * M1 + M1 / 4;
        __bf16* x2  = QKb;
        __bf16* W1T = ws + 12 * M1 + M1 / 4;
        __bf16* Kswz = ws + 16 * M1 + M1 / 4;
        __bf16* ctx  = Kswz;
        __bf16* Vswz = ws + 20 * M1 + M1 / 4;
        __bf16* Opart = ws + 24 * M1 + M1 / 4;
        __bf16* f1  = ws + 16 * M1 + M1 / 4;

        transpose4_cvt<<<dim3(32, 32, 4), tb, 0, stream>>>(Wq, Wk, Wv, Wo,
                                                           WqT, WkT, WvT, WoT, flagF);
        layernorm_k<<<1024, 256, 0, stream>>>(x, 1, flagF, hb, bmir + 10240, bmir + 10241);
        gemm_bt<<<dim3(16, 32), 256, 0, stream>>>(hb, 1024, WqT, 1024, bmir + 1024, nullptr,
                                                  nullptr, 0, flagF, QKb, 0, 4096, 2048, 1024, 0,
                                                  Kswz, 1);
        gemm_n64<<<dim3(64, 8), 256, 0, stream>>>(WvT, 1024, hb, 1024, nullptr, bmir + 3072,
                                                  nullptr, 0, flagF, nullptr, 0, 1024, 4096, 1024, 0,
                                                  Vswz, 2);
        attn_ks2<<<dim3(32, 16, 2), 256, 0, stream>>>(QKb, 2048, Kswz, Vswz, Opart, lpart);
        attn_comb<<<512, 256, 0, stream>>>(Opart, lpart, ctx);
        transpose_cvt<<<dim3(128, 32), tb, 0, stream>>>(W1, W1T, 1024, 4096, flagF);
        gemm_n64<<<dim3(16, 32), 256, 0, stream>>>(ctx, 1024, WoT, 1024, bmir + 4096, nullptr,
                                                   x, 2, flagF, x2, 0, 4096, 1024, 1024, 0,
                                                   nullptr, 0);
        transpose_cvt<<<dim3(32, 128), tb, 0, stream>>>(W2, W2T, 4096, 1024, flagF);
        layernorm_k<<<1024, 256, 0, stream>>>(x2, 0, flagF, h2, bmir + 10242, bmir + 10243);
        gemm_8ph<<<dim3(16, 16), 512, 0, stream>>>(h2, 1024, W1T, 1024, bmir + 5120,
                                                   f1, 4096, 4096, 1024, 1);
        gemm_n64<<<dim3(16, 32), 256, 0, stream>>>(f1, 4096, W2T, 4096, bmir + 9216, nullptr,
                                                   x2, 1, flagF, d_out, 1, 4096, 1024, 4096, 0,
                                                   nullptr, 0);
    } else {
        constexpr size_t Qn = 1u << 18;
        __bf16* WqT = ws + Qn;
        __bf16* WoT = WqT;
        __bf16* WkT = ws + 5 * Qn;
        __bf16* WvT = ws + 9 * Qn;
        __bf16* hb  = ws + 13 * Qn;
        __bf16* f1q = hb;
        __bf16* ctx = ws + 29 * Qn;
        __bf16* W2T = ctx;
        __bf16* QKb = ws + 45 * Qn;
        __bf16* x2  = QKb;
        __bf16* Kb  = ws + 61 * Qn;
        __bf16* h2  = Kb;
        __bf16* VTb = ws + 77 * Qn;
        __bf16* W1T = VTb;
        transpose_cvt<<<dim3(32, 32), tb, 0, stream>>>(Wq, WqT, 1024, 1024, flagF);
        transpose_cvt<<<dim3(32, 32), tb, 0, stream>>>(Wk, WkT, 1024, 1024, flagF);
        transpose_cvt<<<dim3(32, 32), tb, 0, stream>>>(Wv, WvT, 1024, 1024, flagF);
        layernorm_k<<<1024, 256, 0, stream>>>(x, 1, flagF, hb, bmir + 10240, bmir + 10241);
        gemm_bt<<<dim3(8, 32), 256, 0, stream>>>(hb, 1024, WqT, 1024, bmir + 1024, nullptr,
                                                 nullptr, 0, flagF, QKb, 0, 4096, 1024, 1024, 0,
                                                 nullptr, 0);
        gemm_bt<<<dim3(8, 32), 256, 0, stream>>>(hb, 1024, WkT, 1024, bmir + 2048, nullptr,
                                                 nullptr, 0, flagF, Kb, 0, 4096, 1024, 1024, 0,
                                                 nullptr, 0);
        gemm_n64<<<dim3(64, 8), 256, 0, stream>>>(WvT, 1024, hb, 1024, nullptr, bmir + 3072,
                                                  nullptr, 0, flagF, VTb, 0, 1024, 4096, 1024, 0,
                                                  nullptr, 0);
        attn_v3<<<dim3(32, 16), 256, 0, stream>>>(QKb, 1024, Kb, 1024, VTb, ctx);
        transpose_cvt<<<dim3(32, 32), tb, 0, stream>>>(Wo, WoT, 1024, 1024, flagF);
        gemm_n64<<<dim3(16, 32), 256, 0, stream>>>(ctx, 1024, WoT, 1024, bmir + 4096, nullptr,
                                                   x, 2, flagF, x2, 0, 4096, 1024, 1024, 0,
                                                   nullptr, 0);
        layernorm_k<<<1024, 256, 0, stream>>>(x2, 0, flagF, h2, bmir + 10242, bmir + 10243);
        transpose_cvt<<<dim3(128, 32), tb, 0, stream>>>(W1, W1T, 1024, 4096, flagF);
        transpose_cvt<<<dim3(32, 128), tb, 0, stream>>>(W2, W2T, 4096, 1024, flagF);
        for (int ck = 0; ck < 2; ++ck) {
            gemm_bt<<<dim3(16, 32), 256, 0, stream>>>(h2, 1024, W1T + (size_t)ck * 2048 * 1024,
                                                      1024, bmir + 5120 + ck * 2048, nullptr,
                                                      nullptr, 0, flagF, f1q, 0, 4096, 2048, 1024, 1,
                                                      nullptr, 0);
            gemm_n64<<<dim3(16, 32), 256, 0, stream>>>(f1q, 2048, W2T + ck * 2048, 4096,
                                                       ck == 0 ? bmir + 9216 : nullptr, nullptr,
                                                       x2, 1, flagF, ck == 1 ? d_out : (void*)x2,
                                                       ck == 1 ? 1 : 0, 4096, 1024, 2048, 0,
                                                       nullptr, 0);
        }
    }
}

// Round 9
// 451.349 us; speedup vs baseline: 1.0935x; 1.0234x over previous
//
#include <hip/hip_runtime.h>
#include <hip/hip_bf16.h>

typedef __attribute__((ext_vector_type(8))) __bf16 bf16x8;
typedef __attribute__((ext_vector_type(4))) float f32x4;
typedef __attribute__((ext_vector_type(4))) short sh4;
typedef __attribute__((ext_vector_type(8))) short sh8;

#define MFMA(a, b, c) __builtin_amdgcn_mfma_f32_16x16x32_bf16(a, b, c, 0, 0, 0)

#if __has_builtin(__builtin_amdgcn_exp2f)
#define EXP2(x) __builtin_amdgcn_exp2f(x)
#else
#define EXP2(x) exp2f(x)
#endif

// K=32 B-frag / V-frag pairing: slot s = lg*8 + c*4 + r <-> kv-row c*16 + lg*4 + r.
union P8 { struct { sh4 lo, hi; } p; sh8 v; };

__device__ __forceinline__ sh4 pk4(float a, float b, float c, float d) {
    __hip_bfloat162 lo = __float22bfloat162_rn(float2{a, b});
    __hip_bfloat162 hi = __float22bfloat162_rn(float2{c, d});
    union { struct { __hip_bfloat162 lo, hi; } p; sh4 s; } u;
    u.p.lo = lo; u.p.hi = hi;
    return u.s;
}

__device__ __forceinline__ float ldany(const void* p, size_t i, bool f32) {
    return f32 ? ((const float*)p)[i] : (float)(((const __bf16*)p)[i]);
}

// T1: XCD-aware bijective remap (chunked). Bijective when nwg%8==0; identity otherwise.
__device__ __forceinline__ void xcd_remap(int& bx, int& by) {
    int nx = gridDim.x;
    int nwg = nx * gridDim.y;
    int bid = by * nx + bx;
    if ((nwg & 7) == 0) {
        int id = (bid & 7) * (nwg >> 3) + (bid >> 3);
        bx = id % nx;
        by = id / nx;
    }
}

// ---------------------------------------------------------------------------
__global__ void prep_k(const void* wq, float* flag,
                       const void* bq, const void* bk, const void* bv, const void* bo,
                       const void* b1, const void* b2,
                       const void* l1a, const void* l1b, const void* l2a, const void* l2b,
                       __bf16* dst) {
    __shared__ float red[256];
    __shared__ float fls;
    int tid = threadIdx.x;
    const __bf16* p = (const __bf16*)wq;
    float mx = 0.f;
    for (int i = tid; i < 1024; i += 256) {
        float v = (float)p[i];
        if (v != v) mx = 2.f;
        v = fabsf(v);
        if (v > mx) mx = v;
    }
    red[tid] = mx;
    __syncthreads();
    for (int s = 128; s > 0; s >>= 1) {
        if (tid < s) red[tid] = fmaxf(red[tid], red[tid + s]);
        __syncthreads();
    }
    if (tid == 0) { fls = (red[0] > 1.0f) ? 1.f : 0.f; *flag = fls; }
    __syncthreads();
    bool f32 = fls > 0.5f;
    const void* srcs[10] = {bq, bk, bv, bo, b1, b2, l1a, l1b, l2a, l2b};
    const int offs[10] = {1024, 2048, 3072, 4096, 5120, 9216, 10240, 10241, 10242, 10243};
    const int ns[10]   = {1024, 1024, 1024, 1024, 4096, 1024, 1, 1, 1, 1};
    for (int t = 0; t < 10; ++t)
        for (int j = tid; j < ns[t]; j += blockDim.x)
            dst[offs[t] + j] = (__bf16)ldany(srcs[t], j, f32);
}

// ---------------------------------------------------------------------------
__device__ __forceinline__ void tr_body(const void* in, __bf16* out, int R, int C, bool f32,
                                        int bx, int by, int x, int y) {
    __shared__ __bf16 t[32][33];
    for (int i = 0; i < 32; i += 8)
        t[y + i][x] = (__bf16)ldany(in, (size_t)(by + y + i) * C + bx + x, f32);
    __syncthreads();
    for (int i = 0; i < 32; i += 8)
        out[(size_t)(bx + y + i) * R + by + x] = t[x][y + i];
}

__global__ void transpose_cvt(const void* in, __bf16* out, int R, int C, const float* flag) {
    tr_body(in, out, R, C, *flag > 0.5f, blockIdx.x * 32, blockIdx.y * 32,
            threadIdx.x, threadIdx.y);
}

__global__ void transpose4_cvt(const void* i0, const void* i1, const void* i2, const void* i3,
                               __bf16* o0, __bf16* o1, __bf16* o2, __bf16* o3,
                               const float* flag) {
    const void* in = blockIdx.z == 0 ? i0 : blockIdx.z == 1 ? i1 : blockIdx.z == 2 ? i2 : i3;
    __bf16* out = blockIdx.z == 0 ? o0 : blockIdx.z == 1 ? o1 : blockIdx.z == 2 ? o2 : o3;
    tr_body(in, out, 1024, 1024, *flag > 0.5f, blockIdx.x * 32, blockIdx.y * 32,
            threadIdx.x, threadIdx.y);
}

// ---------------------------------------------------------------------------
__global__ __launch_bounds__(256) void layernorm_k(const void* x, int xmode, const float* flag,
                                                   __bf16* out,
                                                   const __bf16* alpha, const __bf16* beta) {
    int row = blockIdx.x * 4 + (threadIdx.x >> 6);
    int lane = threadIdx.x & 63;
    bool f32 = xmode && (*flag > 0.5f);
    float v[16];
    if (f32) {
        const float4* xr = (const float4*)((const float*)x + (size_t)row * 1024 + lane * 16);
#pragma unroll
        for (int q = 0; q < 4; ++q) {
            float4 r = xr[q];
            v[q * 4 + 0] = r.x; v[q * 4 + 1] = r.y; v[q * 4 + 2] = r.z; v[q * 4 + 3] = r.w;
        }
    } else {
        const __bf16* xr = (const __bf16*)x + (size_t)row * 1024 + lane * 16;
        bf16x8 h0 = *(const bf16x8*)xr;
        bf16x8 h1 = *(const bf16x8*)(xr + 8);
#pragma unroll
        for (int i = 0; i < 8; ++i) { v[i] = (float)h0[i]; v[8 + i] = (float)h1[i]; }
    }
    float s = 0.f, ss = 0.f;
#pragma unroll
    for (int i = 0; i < 16; ++i) { s += v[i]; ss += v[i] * v[i]; }
#pragma unroll
    for (int o = 1; o < 64; o <<= 1) { s += __shfl_xor(s, o); ss += __shfl_xor(ss, o); }
    float mu = s * (1.f / 1024.f);
    float var = (ss - 1024.f * mu * mu) * (1.f / 1023.f);
    float inv = 1.f / (sqrtf(var) + 1e-6f);
    float al = (float)alpha[0], be = (float)beta[0];
    bf16x8 o0, o1;
#pragma unroll
    for (int i = 0; i < 8; ++i) {
        o0[i] = (__bf16)((v[i] - mu) * inv * al + be);
        o1[i] = (__bf16)((v[8 + i] - mu) * inv * al + be);
    }
    __bf16* orow = out + (size_t)row * 1024;
    *(bf16x8*)(orow + lane * 16) = o0;
    *(bf16x8*)(orow + lane * 16 + 8) = o1;
}

// Swizzled-tile store helpers: 64x64 tiles, chunk (8 halves) XOR'd by row&7.
__device__ __forceinline__ void swz_store(__bf16* buf, int hh, int ktt, int rr2, int cc2,
                                          float v) {
    size_t off = (((size_t)hh * 64 + ktt) << 12) + rr2 * 64 +
                 (((cc2 >> 3) ^ (rr2 & 7)) << 3) + (cc2 & 7);
    buf[off] = (__bf16)v;
}

// ---------------------------------------------------------------------------
// GEMM 128x128 (256 thr), double-buffered, counted vmcnt, T1 remap.
// ---------------------------------------------------------------------------
__global__ __launch_bounds__(256) void gemm_bt(const __bf16* __restrict__ A, int lda,
                                               const __bf16* __restrict__ Bt, int ldb,
                                               const __bf16* __restrict__ bias_n,
                                               const __bf16* __restrict__ bias_m,
                                               const void* res, int res_mode,
                                               const float* flag,
                                               void* C, int out_pf,
                                               int M, int N, int K, int relu,
                                               __bf16* swzbuf, int swz) {
    __shared__ __bf16 As[2][128 * 32];
    __shared__ __bf16 Bs[2][128 * 32];
    const int tid = threadIdx.x;
    int bx = blockIdx.x, by = blockIdx.y;
    xcd_remap(bx, by);
    const int m0 = by * 128;
    const int n0 = bx * 128;
    const int w = tid >> 6, lane = tid & 63;
    const int wr = (w >> 1) * 64, wc = (w & 1) * 64;
    const int lm = lane & 15, lg = lane >> 4;
    const bool f32 = *flag > 0.5f;
    const bool rf32 = (res_mode == 2) && f32;
    const bool of32 = out_pf && f32;

    auto stage = [&](int buf, int k0) {
#pragma unroll
        for (int i = 0; i < 2; ++i) {
            int c = i * 256 + tid;
            int row = c >> 2, kk = (c & 3) * 8;
            __builtin_amdgcn_global_load_lds(
                (const __attribute__((address_space(1))) void*)(A + (size_t)(m0 + row) * lda + k0 + kk),
                (__attribute__((address_space(3))) void*)(As[buf] + c * 8), 16, 0, 0);
            __builtin_amdgcn_global_load_lds(
                (const __attribute__((address_space(1))) void*)(Bt + (size_t)(n0 + row) * ldb + k0 + kk),
                (__attribute__((address_space(3))) void*)(Bs[buf] + c * 8), 16, 0, 0);
        }
    };

    f32x4 acc[4][4] = {};
    stage(0, 0);
    int cur = 0;
    for (int k0 = 0; k0 < K; k0 += 32) {
        if (k0 + 32 < K) {
            stage(cur ^ 1, k0 + 32);
            asm volatile("s_waitcnt vmcnt(4)" ::: "memory");
        } else {
            asm volatile("s_waitcnt vmcnt(0)" ::: "memory");
        }
        __builtin_amdgcn_s_barrier();
        bf16x8 a[4], b[4];
#pragma unroll
        for (int t = 0; t < 4; ++t)
            a[t] = *(const bf16x8*)(As[cur] + (wr + t * 16 + lm) * 32 + lg * 8);
#pragma unroll
        for (int t = 0; t < 4; ++t)
            b[t] = *(const bf16x8*)(Bs[cur] + (wc + t * 16 + lm) * 32 + lg * 8);
#pragma unroll
        for (int mt = 0; mt < 4; ++mt)
#pragma unroll
            for (int nt = 0; nt < 4; ++nt)
                acc[mt][nt] = MFMA(a[mt], b[nt], acc[mt][nt]);
        asm volatile("s_waitcnt lgkmcnt(0)" ::: "memory");
        __builtin_amdgcn_sched_barrier(0);
        __builtin_amdgcn_s_barrier();
        cur ^= 1;
    }
#pragma unroll
    for (int mt = 0; mt < 4; ++mt) {
#pragma unroll
        for (int nt = 0; nt < 4; ++nt) {
            int col = n0 + wc + nt * 16 + lm;
            float bn = bias_n ? (float)bias_n[col] : 0.f;
#pragma unroll
            for (int r = 0; r < 4; ++r) {
                int row = m0 + wr + mt * 16 + lg * 4 + r;
                float vv = acc[mt][nt][r] + bn;
                if (bias_m) vv += (float)bias_m[row];
                if (relu) vv = fmaxf(vv, 0.f);
                if (swz == 1 && col >= 1024) {
                    swz_store(swzbuf, (col - 1024) >> 6, row >> 6, row & 63, (col - 1024) & 63, vv);
                } else if (swz == 2) {
                    swz_store(swzbuf, row >> 6, col >> 6, row & 63, col & 63, vv);
                } else {
                    size_t idx = (size_t)row * N + col;
                    if (res_mode) vv += rf32 ? ((const float*)res)[idx]
                                             : (float)(((const __bf16*)res)[idx]);
                    if (of32) ((float*)C)[idx] = vv;
                    else ((__bf16*)C)[idx] = (__bf16)vv;
                }
            }
        }
    }
}

// ---------------------------------------------------------------------------
// GEMM 128x64 (256 thr), BK=64, double-buffered, counted vmcnt(6), T1 remap.
// ---------------------------------------------------------------------------
__global__ __launch_bounds__(256) void gemm_n64(const __bf16* __restrict__ A, int lda,
                                                const __bf16* __restrict__ Bt, int ldb,
                                                const __bf16* __restrict__ bias_n,
                                                const __bf16* __restrict__ bias_m,
                                                const void* res, int res_mode,
                                                const float* flag,
                                                void* C, int out_pf,
                                                int M, int N, int K, int relu,
                                                __bf16* swzbuf, int swz) {
    __shared__ __bf16 As[2][128 * 64];
    __shared__ __bf16 Bs[2][64 * 64];
    const int tid = threadIdx.x;
    int bx = blockIdx.x, by = blockIdx.y;
    xcd_remap(bx, by);
    const int m0 = by * 128;
    const int n0 = bx * 64;
    const int w = tid >> 6, lane = tid & 63;
    const int wr = (w >> 1) * 64, wc = (w & 1) * 32;
    const int lm = lane & 15, lg = lane >> 4;
    const int sw = lm & 7;
    const bool f32 = *flag > 0.5f;
    const bool rf32 = (res_mode == 2) && f32;
    const bool of32 = out_pf && f32;

    auto stage = [&](int buf, int k0) {
#pragma unroll
        for (int i = 0; i < 4; ++i) {
            int c = i * 256 + tid;
            int row = c >> 3, ch = c & 7;
            __builtin_amdgcn_global_load_lds(
                (const __attribute__((address_space(1))) void*)(A + (size_t)(m0 + row) * lda + k0 + ((ch ^ (row & 7)) << 3)),
                (__attribute__((address_space(3))) void*)(As[buf] + c * 8), 16, 0, 0);
        }
#pragma unroll
        for (int i = 0; i < 2; ++i) {
            int c = i * 256 + tid;
            int row = c >> 3, ch = c & 7;
            __builtin_amdgcn_global_load_lds(
                (const __attribute__((address_space(1))) void*)(Bt + (size_t)(n0 + row) * ldb + k0 + ((ch ^ (row & 7)) << 3)),
                (__attribute__((address_space(3))) void*)(Bs[buf] + c * 8), 16, 0, 0);
        }
    };

    f32x4 acc[4][2] = {};
    stage(0, 0);
    int cur = 0;
    for (int k0 = 0; k0 < K; k0 += 64) {
        if (k0 + 64 < K) {
            stage(cur ^ 1, k0 + 64);
            asm volatile("s_waitcnt vmcnt(6)" ::: "memory");
        } else {
            asm volatile("s_waitcnt vmcnt(0)" ::: "memory");
        }
        __builtin_amdgcn_s_barrier();
        bf16x8 a[4][2], b[2][2];
#pragma unroll
        for (int t = 0; t < 4; ++t)
#pragma unroll
            for (int h = 0; h < 2; ++h)
                a[t][h] = *(const bf16x8*)(As[cur] + (wr + t * 16 + lm) * 64 + ((((h << 2) | lg) ^ sw) << 3));
#pragma unroll
        for (int t = 0; t < 2; ++t)
#pragma unroll
            for (int h = 0; h < 2; ++h)
                b[t][h] = *(const bf16x8*)(Bs[cur] + (wc + t * 16 + lm) * 64 + ((((h << 2) | lg) ^ sw) << 3));
#pragma unroll
        for (int mt = 0; mt < 4; ++mt)
#pragma unroll
            for (int nt = 0; nt < 2; ++nt) {
                acc[mt][nt] = MFMA(a[mt][0], b[nt][0], acc[mt][nt]);
                acc[mt][nt] = MFMA(a[mt][1], b[nt][1], acc[mt][nt]);
            }
        asm volatile("s_waitcnt lgkmcnt(0)" ::: "memory");
        __builtin_amdgcn_sched_barrier(0);
        __builtin_amdgcn_s_barrier();
        cur ^= 1;
    }
#pragma unroll
    for (int mt = 0; mt < 4; ++mt) {
#pragma unroll
        for (int nt = 0; nt < 2; ++nt) {
            int col = n0 + wc + nt * 16 + lm;
            float bn = bias_n ? (float)bias_n[col] : 0.f;
#pragma unroll
            for (int r = 0; r < 4; ++r) {
                int row = m0 + wr + mt * 16 + lg * 4 + r;
                float vv = acc[mt][nt][r] + bn;
                if (bias_m) vv += (float)bias_m[row];
                if (relu) vv = fmaxf(vv, 0.f);
                if (swz == 2) {
                    swz_store(swzbuf, row >> 6, col >> 6, row & 63, col & 63, vv);
                } else {
                    size_t idx = (size_t)row * N + col;
                    if (res_mode) vv += rf32 ? ((const float*)res)[idx]
                                             : (float)(((const __bf16*)res)[idx]);
                    if (of32) ((float*)C)[idx] = vv;
                    else ((__bf16*)C)[idx] = (__bf16)vv;
                }
            }
        }
    }
}

// ---------------------------------------------------------------------------
// GEMM 256x256, faithful m201 8-phase QUADRANT schedule.
// 512 thr = 8 waves (2M x 4N). Wave output = 4 scattered 64x32 quadrant
// pieces: rows mh*128 + wm*64 + q*16, cols nh*128 + wn*32 + nt*16.
// Phase (mh,nh) order (0,0),(0,1),(1,1),(1,0) -> each phase reads ONE A-half
// + ONE B-half (12 ds_read_b128), stages ONE half-tile (2 gload_lds), and the
// steady-state wait is vmcnt(4) — never 0 (m218 lever). Staging order per
// tile: [A-h0, B-h0, B-h1, A-h1] -> every consumed half is >=3 phases old.
// Per phase: vmcnt -> barrier -> 12 ds_read | stage -> lgkmcnt(0)+fence ->
// setprio(1) 16 MFMA setprio(0) -> barrier. 128 KiB LDS, chunk-XOR swizzle.
// Requires K%128==0, M%256==0, N%256==0.
// ---------------------------------------------------------------------------
__global__ __launch_bounds__(512) void gemm_8ph(const __bf16* __restrict__ A, int lda,
                                                const __bf16* __restrict__ Bt, int ldb,
                                                const __bf16* __restrict__ bias_n,
                                                __bf16* __restrict__ C,
                                                int M, int N, int K, int relu) {
    __shared__ __bf16 As8[4 * 8192];   // [dbuf][half][128][64]
    __shared__ __bf16 Bs8[4 * 8192];
    const int tid = threadIdx.x;
    int bx = blockIdx.x, by = blockIdx.y;
    xcd_remap(bx, by);
    const int m0 = by * 256, n0 = bx * 256;
    const int w = tid >> 6, lane = tid & 63;
    const int lm = lane & 15, lg = lane >> 4;
    const int wm = w >> 2, wn = w & 3;
    const int sw = lm & 7;

    // Stage ONE half-tile (128 rows x 64 K) of an operand: 2 load-rounds.
    auto stageH = [&](const __bf16* src, int ld, __bf16* dst, int rbase, int k0) {
#pragma unroll
        for (int i = 0; i < 2; ++i) {
            int c = i * 512 + tid;             // 0..1023
            int row = c >> 3, ch = c & 7;      // row 0..127 within half
            __builtin_amdgcn_global_load_lds(
                (const __attribute__((address_space(1))) void*)(src + (size_t)(rbase + row) * ld + k0 + ((ch ^ (row & 7)) << 3)),
                (__attribute__((address_space(3))) void*)(dst + c * 8), 16, 0, 0);
        }
    };
    // slot s in [A-h0, B-h0, B-h1, A-h1] of dbuf d at k-offset k0.
    auto stageSlot = [&](int s, int d, int k0) {
        if (s == 0)      stageH(A,  lda, As8 + (d * 2 + 0) * 8192, m0,       k0);
        else if (s == 1) stageH(Bt, ldb, Bs8 + (d * 2 + 0) * 8192, n0,       k0);
        else if (s == 2) stageH(Bt, ldb, Bs8 + (d * 2 + 1) * 8192, n0 + 128, k0);
        else             stageH(A,  lda, As8 + (d * 2 + 1) * 8192, m0 + 128, k0);
    };

    f32x4 acc[2][2][4][2] = {};            // [mh][nh][q][nt]
    const int NI = K >> 7;                 // iterations of 2 K-tiles

    // Prologue: tile 0 into dbuf0, order A0h0,B0h0,B0h1,A0h1 (8 loads).
    stageSlot(0, 0, 0);
    stageSlot(1, 0, 0);
    stageSlot(2, 0, 0);
    stageSlot(3, 0, 0);

    for (int i = 0; i < NI; ++i) {
        const int k1 = (2 * i + 1) * 64;
        const int k2 = (2 * i + 2) * 64;
        const bool has2 = k2 < K;
#pragma unroll
        for (int ph = 0; ph < 8; ++ph) {
            const int dbuf = ph >> 2;
            const int pi = ph & 3;
            const int mh = (pi < 2) ? 0 : 1;              // (0,0),(0,1),(1,1),(1,0)
            const int nh = (pi == 1 || pi == 2) ? 1 : 0;
            // counted wait: leave last-2-phases' stages (4 loads) in flight
            if (ph < 4 || has2) {
                asm volatile("s_waitcnt vmcnt(4)" ::: "memory");
            } else if (ph == 4) {
                asm volatile("s_waitcnt vmcnt(4)" ::: "memory");
            } else if (ph == 5) {
                asm volatile("s_waitcnt vmcnt(2)" ::: "memory");
            } else {
                asm volatile("s_waitcnt vmcnt(0)" ::: "memory");
            }
            __builtin_amdgcn_s_barrier();   // staged data visible to all waves
            const __bf16* Ab = As8 + (dbuf * 2 + mh) * 8192;
            const __bf16* Bb = Bs8 + (dbuf * 2 + nh) * 8192;
            bf16x8 areg[4][2], breg[2][2];
#pragma unroll
            for (int q = 0; q < 4; ++q) {
                int rr = wm * 64 + q * 16 + lm;
#pragma unroll
                for (int kk = 0; kk < 2; ++kk)
                    areg[q][kk] = *(const bf16x8*)(Ab + rr * 64 + (((kk * 4 + lg) ^ sw) << 3));
            }
#pragma unroll
            for (int nt = 0; nt < 2; ++nt) {
                int rr = wn * 32 + nt * 16 + lm;
#pragma unroll
                for (int kk = 0; kk < 2; ++kk)
                    breg[nt][kk] = *(const bf16x8*)(Bb + rr * 64 + (((kk * 4 + lg) ^ sw) << 3));
            }
            // stage one half-tile into the opposite dbuf (dead region)
            if (ph < 4) stageSlot(pi, 1, k1);
            else if (has2) stageSlot(pi, 0, k2);
            asm volatile("s_waitcnt lgkmcnt(0)" ::: "memory");
            __builtin_amdgcn_sched_barrier(0);
            __builtin_amdgcn_s_setprio(1);
#pragma unroll
            for (int q = 0; q < 4; ++q)
#pragma unroll
                for (int nt = 0; nt < 2; ++nt)
#pragma unroll
                    for (int kk = 0; kk < 2; ++kk)
                        acc[mh][nh][q][nt] = MFMA(areg[q][kk], breg[nt][kk], acc[mh][nh][q][nt]);
            __builtin_amdgcn_s_setprio(0);
            __builtin_amdgcn_s_barrier();   // reads done (lgkm 0) -> region reusable
        }
    }
#pragma unroll
    for (int mh = 0; mh < 2; ++mh)
#pragma unroll
        for (int q = 0; q < 4; ++q)
#pragma unroll
            for (int nh = 0; nh < 2; ++nh)
#pragma unroll
                for (int nt = 0; nt < 2; ++nt) {
                    int col = n0 + nh * 128 + wn * 32 + nt * 16 + lm;
                    float bn = bias_n ? (float)bias_n[col] : 0.f;
#pragma unroll
                    for (int r = 0; r < 4; ++r) {
                        int row = m0 + mh * 128 + wm * 64 + q * 16 + lg * 4 + r;
                        float vv = acc[mh][nh][q][nt][r] + bn;
                        if (relu) vv = fmaxf(vv, 0.f);
                        C[(size_t)row * N + col] = (__bf16)vv;
                    }
                }
}

// ---------------------------------------------------------------------------
// Attention v7: K=32 PV via kv-permutation.
// ---------------------------------------------------------------------------
__global__ __launch_bounds__(256) void attn_ks2(const __bf16* __restrict__ Q, int ldq,
                                                const __bf16* __restrict__ Kswz,
                                                const __bf16* __restrict__ Vswz,
                                                __bf16* __restrict__ Opart,
                                                float* __restrict__ lpart) {
    constexpr int S = 4096;
    __shared__ __bf16 lds[2 * 8192];
    const int h = blockIdx.y, z = blockIdx.z;
    const int q0 = blockIdx.x * 128;
    const int tid = threadIdx.x, w = tid >> 6, lane = tid & 63;
    const int lm = lane & 15, lg = lane >> 4;

    const __bf16* gK = Kswz + (((size_t)h * 64 + z * 32) << 12);
    const __bf16* gV = Vswz + (((size_t)h * 64 + z * 32) << 12);

    bf16x8 qf[2][2];
#pragma unroll
    for (int qc = 0; qc < 2; ++qc) {
        const __bf16* qp = Q + (size_t)(q0 + w * 32 + qc * 16 + lm) * ldq + h * 64;
        qf[qc][0] = *(const bf16x8*)(qp + lg * 8);
        qf[qc][1] = *(const bf16x8*)(qp + 32 + lg * 8);
#pragma unroll
        for (int hh = 0; hh < 2; ++hh) {
            bf16x8 t = qf[qc][hh];
#pragma unroll
            for (int i = 0; i < 8; ++i) t[i] = (__bf16)((float)t[i] * 0.1803368801f);
            qf[qc][hh] = t;
        }
    }
    bf16x8 ones8;
#pragma unroll
    for (int i = 0; i < 8; ++i) ones8[i] = (__bf16)1.f;

    f32x4 o_[4][2] = {};
    f32x4 l_[2] = {};

    auto issue = [&](int t) {
        __bf16* dK = lds + (t & 1) * 8192;
        __bf16* dV = dK + 4096;
        const __bf16* sK = gK + ((size_t)t << 12);
        const __bf16* sV = gV + ((size_t)t << 12);
#pragma unroll
        for (int i = 0; i < 2; ++i) {
            int c = i * 256 + tid;
            __builtin_amdgcn_global_load_lds(
                (const __attribute__((address_space(1))) void*)(sK + c * 8),
                (__attribute__((address_space(3))) void*)(dK + c * 8), 16, 0, 0);
            __builtin_amdgcn_global_load_lds(
                (const __attribute__((address_space(1))) void*)(sV + c * 8),
                (__attribute__((address_space(3))) void*)(dV + c * 8), 16, 0, 0);
        }
    };
    issue(0);
    for (int t = 0; t < 32; ++t) {
        __syncthreads();
        if (t < 31) issue(t + 1);
        const __bf16* Kt = lds + (t & 1) * 8192;
        const __bf16* Vt = Kt + 4096;

        P8 pb[2][2];
#pragma unroll
        for (int mt = 0; mt < 4; ++mt) {
            int rr = mt * 16 + lm;
            const __bf16* kr = Kt + rr * 64;
            bf16x8 kf0 = *(const bf16x8*)(kr + ((lg ^ (rr & 7)) << 3));
            bf16x8 kf1 = *(const bf16x8*)(kr + (((4 + lg) ^ (rr & 7)) << 3));
#pragma unroll
            for (int qc = 0; qc < 2; ++qc) {
                f32x4 s = (f32x4){0.f, 0.f, 0.f, 0.f};
                s = MFMA(kf0, qf[qc][0], s);
                s = MFMA(kf1, qf[qc][1], s);
                sh4 e = pk4(EXP2(s[0]), EXP2(s[1]), EXP2(s[2]), EXP2(s[3]));
                if (mt & 1) pb[mt >> 1][qc].p.hi = e;
                else        pb[mt >> 1][qc].p.lo = e;
            }
        }
#pragma unroll
        for (int mtd = 0; mtd < 4; ++mtd) {
            int rr = mtd * 16 + lm;
            const __bf16* vr = Vt + rr * 64;
#pragma unroll
            for (int cp = 0; cp < 2; ++cp) {
                int cbase = cp * 4 + (lg >> 1);
                P8 va;
                va.p.lo = *(const sh4*)(vr + ((cbase ^ (rr & 7)) << 3) + (lg & 1) * 4);
                va.p.hi = *(const sh4*)(vr + (((cbase + 2) ^ (rr & 7)) << 3) + (lg & 1) * 4);
                bf16x8 vab = __builtin_bit_cast(bf16x8, va.v);
                o_[mtd][0] = MFMA(vab, __builtin_bit_cast(bf16x8, pb[cp][0].v), o_[mtd][0]);
                o_[mtd][1] = MFMA(vab, __builtin_bit_cast(bf16x8, pb[cp][1].v), o_[mtd][1]);
            }
        }
#pragma unroll
        for (int cp = 0; cp < 2; ++cp) {
            l_[0] = MFMA(ones8, __builtin_bit_cast(bf16x8, pb[cp][0].v), l_[0]);
            l_[1] = MFMA(ones8, __builtin_bit_cast(bf16x8, pb[cp][1].v), l_[1]);
        }
    }

    __syncthreads();
#pragma unroll
    for (int qc = 0; qc < 2; ++qc) {
#pragma unroll
        for (int mtd = 0; mtd < 4; ++mtd) {
            sh4 ov = pk4(o_[mtd][qc][0], o_[mtd][qc][1], o_[mtd][qc][2], o_[mtd][qc][3]);
            *(sh4*)(lds + (w * 32 + qc * 16 + lm) * 72 + mtd * 16 + lg * 4) = ov;
        }
        if (lg == 0)
            lpart[(size_t)(h * 2 + z) * S + q0 + w * 32 + qc * 16 + lm] = l_[qc][0];
    }
    __syncthreads();
    __bf16* Ob = Opart + (((size_t)(h * 2 + z) * S + q0) << 6);
    int row = tid >> 1, co = (tid & 1) * 32;
#pragma unroll
    for (int b = 0; b < 4; ++b)
        *(uint4*)(Ob + row * 64 + co + b * 8) = *(const uint4*)(lds + row * 72 + co + b * 8);
}

__global__ __launch_bounds__(256) void attn_comb(const __bf16* __restrict__ Opart,
                                                 const float* __restrict__ lpart,
                                                 __bf16* __restrict__ ctx) {
    constexpr int S = 4096;
#pragma unroll
    for (int it = 0; it < 4; ++it) {
        int task = blockIdx.x * 1024 + it * 256 + threadIdx.x;
        int q = task >> 7, c8 = task & 127, h = c8 >> 3, d8 = (c8 & 7) * 8;
        const __bf16* p0 = Opart + (((size_t)(h * 2 + 0) * S + q) << 6) + d8;
        const __bf16* p1 = Opart + (((size_t)(h * 2 + 1) * S + q) << 6) + d8;
        float inv = 1.f / (lpart[(size_t)(h * 2 + 0) * S + q] + lpart[(size_t)(h * 2 + 1) * S + q]);
        bf16x8 a = *(const bf16x8*)p0, b = *(const bf16x8*)p1, o;
#pragma unroll
        for (int i = 0; i < 8; ++i) o[i] = (__bf16)(((float)a[i] + (float)b[i]) * inv);
        *(bf16x8*)(ctx + (size_t)q * 1024 + c8 * 8) = o;
    }
}

// ---------------------------------------------------------------------------
// r6 attention — fallback path only.
// ---------------------------------------------------------------------------
__global__ __launch_bounds__(256) void attn_v3(const __bf16* __restrict__ Q, int ldq,
                                               const __bf16* __restrict__ Kg, int ldk,
                                               const __bf16* __restrict__ VT,
                                               __bf16* __restrict__ ctx) {
    constexpr int S = 4096, D = 1024, LDT = 72;
    __shared__ __bf16 lds[128 * LDT];
    __bf16* Kt = lds;
    __bf16* Vt = lds + 64 * LDT;
    const int h = blockIdx.y;
    const int q0 = blockIdx.x * 128;
    const int tid = threadIdx.x, w = tid >> 6, lane = tid & 63;
    const int lm = lane & 15, lg = lane >> 4;
    bf16x8 qf[2][2];
#pragma unroll
    for (int qc = 0; qc < 2; ++qc) {
        const __bf16* qp = Q + (size_t)(q0 + w * 32 + qc * 16 + lm) * ldq + h * 64;
        qf[qc][0] = *(const bf16x8*)(qp + lg * 8);
        qf[qc][1] = *(const bf16x8*)(qp + 32 + lg * 8);
#pragma unroll
        for (int hh = 0; hh < 2; ++hh) {
            bf16x8 t = qf[qc][hh];
#pragma unroll
            for (int i = 0; i < 8; ++i) t[i] = (__bf16)((float)t[i] * 0.1803368801f);
            qf[qc][hh] = t;
        }
    }
    bf16x8 ones8;
#pragma unroll
    for (int i = 0; i < 8; ++i) ones8[i] = (__bf16)1.f;
    f32x4 o_[4][2] = {};
    f32x4 l_[2] = {};
    for (int kt = 0; kt < S / 64; ++kt) {
        __syncthreads();
#pragma unroll
        for (int i = 0; i < 2; ++i) {
            int c = i * 256 + tid;
            int rr = c >> 3, cc = (c & 7) * 8;
            *(uint4*)(Kt + rr * LDT + cc) =
                *(const uint4*)(Kg + (size_t)(kt * 64 + rr) * ldk + h * 64 + cc);
            *(uint4*)(Vt + rr * LDT + cc) =
                *(const uint4*)(VT + (size_t)(h * 64 + rr) * S + kt * 64 + cc);
        }
        __syncthreads();
        P8 pb[2][2];
#pragma unroll
        for (int mt = 0; mt < 4; ++mt) {
            bf16x8 kf0 = *(const bf16x8*)(Kt + (mt * 16 + lm) * LDT + lg * 8);
            bf16x8 kf1 = *(const bf16x8*)(Kt + (mt * 16 + lm) * LDT + 32 + lg * 8);
#pragma unroll
            for (int qc = 0; qc < 2; ++qc) {
                f32x4 s = (f32x4){0.f, 0.f, 0.f, 0.f};
                s = MFMA(kf0, qf[qc][0], s);
                s = MFMA(kf1, qf[qc][1], s);
                sh4 e = pk4(EXP2(s[0]), EXP2(s[1]), EXP2(s[2]), EXP2(s[3]));
                if (mt & 1) pb[mt >> 1][qc].p.hi = e;
                else        pb[mt >> 1][qc].p.lo = e;
            }
        }
#pragma unroll
        for (int mtd = 0; mtd < 4; ++mtd) {
            const __bf16* vrow = Vt + (mtd * 16 + lm) * LDT;
#pragma unroll
            for (int cp = 0; cp < 2; ++cp) {
                P8 va;
                va.p.lo = *(const sh4*)(vrow + cp * 32 + lg * 4);
                va.p.hi = *(const sh4*)(vrow + cp * 32 + 16 + lg * 4);
                bf16x8 vab = __builtin_bit_cast(bf16x8, va.v);
                o_[mtd][0] = MFMA(vab, __builtin_bit_cast(bf16x8, pb[cp][0].v), o_[mtd][0]);
                o_[mtd][1] = MFMA(vab, __builtin_bit_cast(bf16x8, pb[cp][1].v), o_[mtd][1]);
            }
        }
#pragma unroll
        for (int cp = 0; cp < 2; ++cp) {
            l_[0] = MFMA(ones8, __builtin_bit_cast(bf16x8, pb[cp][0].v), l_[0]);
            l_[1] = MFMA(ones8, __builtin_bit_cast(bf16x8, pb[cp][1].v), l_[1]);
        }
    }
    __syncthreads();
    float inv[2] = {1.f / l_[0][0], 1.f / l_[1][0]};
#pragma unroll
    for (int qc = 0; qc < 2; ++qc)
#pragma unroll
        for (int mtd = 0; mtd < 4; ++mtd)
#pragma unroll
            for (int r = 0; r < 4; ++r)
                lds[(w * 32 + qc * 16 + lm) * LDT + mtd * 16 + lg * 4 + r] =
                    (__bf16)(o_[mtd][qc][r] * inv[qc]);
    __syncthreads();
    int row = tid >> 1, cb = (tid & 1) * 32;
#pragma unroll
    for (int b = 0; b < 4; ++b)
        *(uint4*)(ctx + (size_t)(q0 + row) * D + h * 64 + cb + b * 8) =
            *(const uint4*)(lds + row * LDT + cb + b * 8);
}

// ---------------------------------------------------------------------------
extern "C" void kernel_launch(void* const* d_in, const int* in_sizes, int n_in,
                              void* d_out, int out_size, void* d_ws, size_t ws_size,
                              hipStream_t stream) {
    const void* x    = d_in[0];
    const void* Wq   = d_in[1];
    const void* bq   = d_in[2];
    const void* Wk   = d_in[3];
    const void* bk   = d_in[4];
    const void* Wv   = d_in[5];
    const void* bv   = d_in[6];
    const void* Wo   = d_in[7];
    const void* bo   = d_in[8];
    const void* ln1a = d_in[9];
    const void* ln1b = d_in[10];
    const void* W1   = d_in[11];
    const void* b1   = d_in[12];
    const void* W2   = d_in[13];
    const void* b2   = d_in[14];
    const void* ln2a = d_in[15];
    const void* ln2b = d_in[16];

    constexpr size_t M1 = 1u << 20;
    __bf16* ws = (__bf16*)d_ws;
    float* flagF = (float*)ws;
    __bf16* bmir = ws;
    dim3 tb(32, 8);
    const bool big = ws_size >= (size_t)(32.25 * 2 * M1) + 4096;

    prep_k<<<1, 256, 0, stream>>>(Wq, flagF, bq, bk, bv, bo, b1, b2,
                                  ln1a, ln1b, ln2a, ln2b, bmir);

    if (big) {
        __bf16* WqT = ws + M1 / 4;
        __bf16* WkT = WqT + M1;
        __bf16* WvT = ws + 2 * M1 + M1 / 4;
        __bf16* WoT = ws + 3 * M1 + M1 / 4;
        __bf16* W2T = ws + M1 / 4;
        float* lpart = (float*)(ws + M1 / 4);
        __bf16* hb  = ws + 4 * M1 + M1 / 4;
        __bf16* h2  = hb;
        __bf16* QKb = ws + 8 * M1 + M1 / 4;
        __bf16* x2  = QKb;
        __bf16* W1T = ws + 12 * M1 + M1 / 4;
        __bf16* Kswz = ws + 16 * M1 + M1 / 4;
        __bf16* ctx  = Kswz;
        __bf16* Vswz = ws + 20 * M1 + M1 / 4;
        __bf16* Opart = ws + 24 * M1 + M1 / 4;
        __bf16* f1  = ws + 16 * M1 + M1 / 4;

        transpose4_cvt<<<dim3(32, 32, 4), tb, 0, stream>>>(Wq, Wk, Wv, Wo,
                                                           WqT, WkT, WvT, WoT, flagF);
        layernorm_k<<<1024, 256, 0, stream>>>(x, 1, flagF, hb, bmir + 10240, bmir + 10241);
        gemm_bt<<<dim3(16, 32), 256, 0, stream>>>(hb, 1024, WqT, 1024, bmir + 1024, nullptr,
                                                  nullptr, 0, flagF, QKb, 0, 4096, 2048, 1024, 0,
                                                  Kswz, 1);
        gemm_n64<<<dim3(64, 8), 256, 0, stream>>>(WvT, 1024, hb, 1024, nullptr, bmir + 3072,
                                                  nullptr, 0, flagF, nullptr, 0, 1024, 4096, 1024, 0,
                                                  Vswz, 2);
        attn_ks2<<<dim3(32, 16, 2), 256, 0, stream>>>(QKb, 2048, Kswz, Vswz, Opart, lpart);
        attn_comb<<<512, 256, 0, stream>>>(Opart, lpart, ctx);
        transpose_cvt<<<dim3(128, 32), tb, 0, stream>>>(W1, W1T, 1024, 4096, flagF);
        gemm_n64<<<dim3(16, 32), 256, 0, stream>>>(ctx, 1024, WoT, 1024, bmir + 4096, nullptr,
                                                   x, 2, flagF, x2, 0, 4096, 1024, 1024, 0,
                                                   nullptr, 0);
        transpose_cvt<<<dim3(32, 128), tb, 0, stream>>>(W2, W2T, 4096, 1024, flagF);
        layernorm_k<<<1024, 256, 0, stream>>>(x2, 0, flagF, h2, bmir + 10242, bmir + 10243);
        gemm_8ph<<<dim3(16, 16), 512, 0, stream>>>(h2, 1024, W1T, 1024, bmir + 5120,
                                                   f1, 4096, 4096, 1024, 1);
        gemm_n64<<<dim3(16, 32), 256, 0, stream>>>(f1, 4096, W2T, 4096, bmir + 9216, nullptr,
                                                   x2, 1, flagF, d_out, 1, 4096, 1024, 4096, 0,
                                                   nullptr, 0);
    } else {
        constexpr size_t Qn = 1u << 18;
        __bf16* WqT = ws + Qn;
        __bf16* WoT = WqT;
        __bf16* WkT = ws + 5 * Qn;
        __bf16* WvT = ws + 9 * Qn;
        __bf16* hb  = ws + 13 * Qn;
        __bf16* f1q = hb;
        __bf16* ctx = ws + 29 * Qn;
        __bf16* W2T = ctx;
        __bf16* QKb = ws + 45 * Qn;
        __bf16* x2  = QKb;
        __bf16* Kb  = ws + 61 * Qn;
        __bf16* h2  = Kb;
        __bf16* VTb = ws + 77 * Qn;
        __bf16* W1T = VTb;
        transpose_cvt<<<dim3(32, 32), tb, 0, stream>>>(Wq, WqT, 1024, 1024, flagF);
        transpose_cvt<<<dim3(32, 32), tb, 0, stream>>>(Wk, WkT, 1024, 1024, flagF);
        transpose_cvt<<<dim3(32, 32), tb, 0, stream>>>(Wv, WvT, 1024, 1024, flagF);
        layernorm_k<<<1024, 256, 0, stream>>>(x, 1, flagF, hb, bmir + 10240, bmir + 10241);
        gemm_bt<<<dim3(8, 32), 256, 0, stream>>>(hb, 1024, WqT, 1024, bmir + 1024, nullptr,
                                                 nullptr, 0, flagF, QKb, 0, 4096, 1024, 1024, 0,
                                                 nullptr, 0);
        gemm_bt<<<dim3(8, 32), 256, 0, stream>>>(hb, 1024, WkT, 1024, bmir + 2048, nullptr,
                                                 nullptr, 0, flagF, Kb, 0, 4096, 1024, 1024, 0,
                                                 nullptr, 0);
        gemm_n64<<<dim3(64, 8), 256, 0, stream>>>(WvT, 1024, hb, 1024, nullptr, bmir + 3072,
                                                  nullptr, 0, flagF, VTb, 0, 1024, 4096, 1024, 0,
                                                  nullptr, 0);
        attn_v3<<<dim3(32, 16), 256, 0, stream>>>(QKb, 1024, Kb, 1024, VTb, ctx);
        transpose_cvt<<<dim3(32, 32), tb, 0, stream>>>(Wo, WoT, 1024, 1024, flagF);
        gemm_n64<<<dim3(16, 32), 256, 0, stream>>>(ctx, 1024, WoT, 1024, bmir + 4096, nullptr,
                                                   x, 2, flagF, x2, 0, 4096, 1024, 1024, 0,
                                                   nullptr, 0);
        layernorm_k<<<1024, 256, 0, stream>>>(x2, 0, flagF, h2, bmir + 10242, bmir + 10243);
        transpose_cvt<<<dim3(128, 32), tb, 0, stream>>>(W1, W1T, 1024, 4096, flagF);
        transpose_cvt<<<dim3(32, 128), tb, 0, stream>>>(W2, W2T, 4096, 1024, flagF);
        for (int ck = 0; ck < 2; ++ck) {
            gemm_bt<<<dim3(16, 32), 256, 0, stream>>>(h2, 1024, W1T + (size_t)ck * 2048 * 1024,
                                                      1024, bmir + 5120 + ck * 2048, nullptr,
                                                      nullptr, 0, flagF, f1q, 0, 4096, 2048, 1024, 1,
                                                      nullptr, 0);
            gemm_n64<<<dim3(16, 32), 256, 0, stream>>>(f1q, 2048, W2T + ck * 2048, 4096,
                                                       ck == 0 ? bmir + 9216 : nullptr, nullptr,
                                                       x2, 1, flagF, ck == 1 ? d_out : (void*)x2,
                                                       ck == 1 ? 1 : 0, 4096, 1024, 2048, 0,
                                                       nullptr, 0);
        }
    }
}